// Round 7
// baseline (202.110 us; speedup 1.0000x reference)
//
#include <hip/hip_runtime.h>

// ---------------- types / helpers ----------------
typedef __attribute__((ext_vector_type(8))) __bf16 bf16x8;
typedef __attribute__((ext_vector_type(8))) short short8;
typedef __attribute__((ext_vector_type(4))) float f32x4;
typedef unsigned int u32;

static __device__ __forceinline__ unsigned short f2bf(float f) {
    u32 u = __float_as_uint(f);
    u += 0x7FFFu + ((u >> 16) & 1u);
    return (unsigned short)(u >> 16);
}
static __device__ __forceinline__ u32 cvt_pk_bf16(float lo, float hi) {
    u32 r;
    asm("v_cvt_pk_bf16_f32 %0, %1, %2" : "=v"(r) : "v"(lo), "v"(hi));
    return r;
}
static __device__ __forceinline__ bf16x8 as_bf16x8(short8 v) {
    return __builtin_bit_cast(bf16x8, v);
}
static __device__ __forceinline__ f32x4 mfma16(short8 a, short8 b, f32x4 c) {
    return __builtin_amdgcn_mfma_f32_16x16x32_bf16(as_bf16x8(a), as_bf16x8(b), c, 0, 0, 0);
}

// problem sizes
#define NB 8
#define NS 5
#define NQ 15
// ws layout (floats)
#define A_OFF_F 0
#define B_OFF_F (640*256)                        // 163840
#define XF_OFF_F (B_OFF_F + 1920*256)            // 655360
#define WF_OFF_BYTES ((XF_OFF_F + 600*8*256)*4)  // 7536640, 16B aligned

// ---------------- kernel 1+2 fused ----------------
// blocks 0..639: k1 (A = sup@W1a + b1, B = qry@W1b), 512 thr, (cell, 64-col grp)
// blocks 640..687: k2 (g_w2/3/4 -> bf16 A-frag chunks), 512 thr, one 8KB chunk each.
// wf chunk cid = L*16+tt at byte cid*8192; within: kk*1024 + lane*16; lane l holds
// W[k = kk*32+(l>>4)*8+j][outcol = tt*16+(l&15)], j=0..7 (bf16).
__global__ void k12(const float* __restrict__ sup, const float* __restrict__ qry,
                    const float* __restrict__ gw1, const float* __restrict__ gb1,
                    const float* __restrict__ w2, const float* __restrict__ w3,
                    const float* __restrict__ w4,
                    float* __restrict__ ws, unsigned short* __restrict__ wfout) {
    __shared__ float x[258 * 16];
    int bid = blockIdx.x;
    int t = threadIdx.x;
    if (bid >= 640) {
        int cid = bid - 640;          // 0..47
        int L = cid >> 4, tt = cid & 15;
        int kk = t >> 6, l = t & 63;
        const float* W = (L == 0) ? w2 : ((L == 1) ? w3 : w4);
        int nn = tt * 16 + (l & 15);
        int k0 = kk * 32 + (l >> 4) * 8;
        short8 ov;
        #pragma unroll
        for (int j = 0; j < 8; ++j)
            ov[j] = (short)f2bf(W[(size_t)(k0 + j) * 256 + nn]);
        *(short8*)((char*)wfout + (size_t)cid * 8192 + kk * 1024 + l * 16) = ov;
        return;
    }
    int cg = bid & 3;
    int cid = bid >> 2;
    bool isA = (cid < NB * NS);
    int cell = isA ? cid : (cid - NB * NS);
    const float* src = (isA ? sup : qry) + (size_t)cell * 4096;
    ((float4*)x)[t] = ((const float4*)src)[t];
    ((float4*)x)[t + 512] = ((const float4*)src)[t + 512];
    if (t < 16) {
        x[256 * 16 + t] = (float)(t >> 2) * 0.25f;
        x[257 * 16 + t] = (float)(t & 3) * 0.25f;
    }
    __syncthreads();
    int col = cg * 64 + (t & 63);
    int ng = t >> 6;
    float binit = isA ? gb1[col] : 0.0f;
    float ax = binit, ay = binit;
    int koff = isA ? 0 : 258;
    #pragma unroll 4
    for (int k = 0; k < 258; ++k) {
        float wv = gw1[(size_t)(koff + k) * 256 + col];
        float2 xv = *(const float2*)(x + k * 16 + ng * 2);
        ax += xv.x * wv;
        ay += xv.y * wv;
    }
    float* dst = ws + (isA ? A_OFF_F : B_OFF_F) + ((size_t)cell * 16 + ng * 2) * 256 + col;
    dst[0] = ax;
    dst[256] = ay;
}

// ---------------- kernel 3: g-MLP layers 2..4 + pair-sum (bf16, barrier-free main loop) --
// grid = 600 blocks (one cell = 256 pairs), 512 threads = 8 waves x 32 pairs (2 pair-grps).
// H: 128 KB LDS, bf16 B-frag layout, wave-private. W: bf16 streamed L2->regs, double-
// buffered 8KB chunks, 4 MFMA chains/wave. Biases in LDS (keeps W vmcnt pipeline intact).
#define TT_BODY(WCUR, WOTHER)                                                   \
    {                                                                           \
        int nidx = chunk + 1; if (nidx > 47) nidx = 47;                         \
        float4 bv = *(const float4*)(bs + Loff + tt * 16 + g * 4);              \
        const char* nsrc = wfb + (size_t)nidx * 8192 + l * 16;                  \
        _Pragma("unroll")                                                       \
        for (int kk = 0; kk < 8; ++kk)                                          \
            WOTHER[kk] = *(const short8*)(nsrc + kk * 1024);                    \
        f32x4 a0e = {0.f,0.f,0.f,0.f}, a0o = {0.f,0.f,0.f,0.f};                 \
        f32x4 a1e = {0.f,0.f,0.f,0.f}, a1o = {0.f,0.f,0.f,0.f};                 \
        _Pragma("unroll")                                                       \
        for (int kk = 0; kk < 8; kk += 2) {                                     \
            a0e = mfma16(WCUR[kk], bfr0[kk], a0e);                              \
            a1e = mfma16(WCUR[kk], bfr1[kk], a1e);                              \
            a0o = mfma16(WCUR[kk + 1], bfr0[kk + 1], a0o);                      \
            a1o = mfma16(WCUR[kk + 1], bfr1[kk + 1], a1o);                      \
        }                                                                       \
        f32x4 A0 = a0e + a0o, A1 = a1e + a1o;                                   \
        if (L < 2) {                                                            \
            int kk2 = tt >> 1;                                                  \
            int gp = (tt & 1) * 2 + (g >> 1);                                   \
            int wb = (gp * 16 + c) * 16 + (g & 1) * 8;                          \
            uint2 o0, o1;                                                       \
            o0.x = cvt_pk_bf16(fmaxf(A0[0]+bv.x,0.f), fmaxf(A0[1]+bv.y,0.f));   \
            o0.y = cvt_pk_bf16(fmaxf(A0[2]+bv.z,0.f), fmaxf(A0[3]+bv.w,0.f));   \
            o1.x = cvt_pk_bf16(fmaxf(A1[0]+bv.x,0.f), fmaxf(A1[1]+bv.y,0.f));   \
            o1.y = cvt_pk_bf16(fmaxf(A1[2]+bv.z,0.f), fmaxf(A1[3]+bv.w,0.f));   \
            *(uint2*)(Hb + (size_t)((w2_ + 0) * 8 + kk2) * 1024 + wb) = o0;     \
            *(uint2*)(Hb + (size_t)((w2_ + 1) * 8 + kk2) * 1024 + wb) = o1;     \
        } else {                                                                \
            float s0 = fmaxf(A0[0]+bv.x,0.f) + fmaxf(A1[0]+bv.x,0.f);           \
            float s1 = fmaxf(A0[1]+bv.y,0.f) + fmaxf(A1[1]+bv.y,0.f);           \
            float s2 = fmaxf(A0[2]+bv.z,0.f) + fmaxf(A1[2]+bv.z,0.f);           \
            float s3 = fmaxf(A0[3]+bv.w,0.f) + fmaxf(A1[3]+bv.w,0.f);           \
            s0 += __shfl_xor(s0,1); s0 += __shfl_xor(s0,2);                     \
            s0 += __shfl_xor(s0,4); s0 += __shfl_xor(s0,8);                     \
            s1 += __shfl_xor(s1,1); s1 += __shfl_xor(s1,2);                     \
            s1 += __shfl_xor(s1,4); s1 += __shfl_xor(s1,8);                     \
            s2 += __shfl_xor(s2,1); s2 += __shfl_xor(s2,2);                     \
            s2 += __shfl_xor(s2,4); s2 += __shfl_xor(s2,8);                     \
            s3 += __shfl_xor(s3,1); s3 += __shfl_xor(s3,2);                     \
            s3 += __shfl_xor(s3,4); s3 += __shfl_xor(s3,8);                     \
            if (c == 0) {                                                       \
                float4 o = {s0, s1, s2, s3};                                    \
                *(float4*)(xf + ((size_t)bqs * 8 + w) * 256 + tt * 16 + g * 4) = o; \
            }                                                                   \
        }                                                                       \
        ++chunk;                                                                \
    }

__launch_bounds__(512, 2)
__global__ void k3_g(const float* __restrict__ wsA, const float* __restrict__ wsB,
                     const unsigned short* __restrict__ wf,
                     const float* __restrict__ gb2, const float* __restrict__ gb3,
                     const float* __restrict__ gb4, float* __restrict__ xf) {
    __shared__ short Hf[65536];   // 128 KB: frag(m,kk) at (m*8+kk)*1024 bytes
    __shared__ float bs[768];
    int bqs = blockIdx.x;
    int b = bqs / 75, rem = bqs % 75, qi = rem / 5, si = rem % 5;
    int t = threadIdx.x;
    int w = t >> 6, l = t & 63;
    int g = l >> 4, c = l & 15;
    int w2_ = w * 2;
    char* Hb = (char*)Hf;
    const char* wfb = (const char*)wf;

    if (t < 256) { bs[t] = gb2[t]; bs[256 + t] = gb3[t]; bs[512 + t] = gb4[t]; }

    // W chunk 0 prologue (lands under phase 1)
    short8 wA[8], wB[8];
    #pragma unroll
    for (int kk = 0; kk < 8; ++kk)
        wA[kk] = *(const short8*)(wfb + kk * 1024 + l * 16);

    // ---- phase 1: H1[pair][k] = relu(A[n][k] + B[m][k]) -> bf16 B-frag layout.
    // pair = m*16 + c (m = w2_+pg, n = c); k = kk*32 + g*8 + j.
    {
        const float* Arow = wsA + (size_t)(b * NS + si) * 4096 + c * 256;
        const float* Brow = wsB + (size_t)(b * NQ + qi) * 4096;
        #pragma unroll
        for (int pg = 0; pg < 2; ++pg) {
            int m = w2_ + pg;
            #pragma unroll
            for (int kk = 0; kk < 8; ++kk) {
                const float* ap = Arow + kk * 32 + g * 8;
                const float* bp = Brow + m * 256 + kk * 32 + g * 8;
                float4 a0 = *(const float4*)ap, a1 = *(const float4*)(ap + 4);
                float4 b0 = *(const float4*)bp, b1 = *(const float4*)(bp + 4);
                uint4 hv;
                hv.x = cvt_pk_bf16(fmaxf(a0.x + b0.x, 0.f), fmaxf(a0.y + b0.y, 0.f));
                hv.y = cvt_pk_bf16(fmaxf(a0.z + b0.z, 0.f), fmaxf(a0.w + b0.w, 0.f));
                hv.z = cvt_pk_bf16(fmaxf(a1.x + b1.x, 0.f), fmaxf(a1.y + b1.y, 0.f));
                hv.w = cvt_pk_bf16(fmaxf(a1.z + b1.z, 0.f), fmaxf(a1.w + b1.w, 0.f));
                *(uint4*)(Hb + (size_t)(m * 8 + kk) * 1024 + l * 16) = hv;
            }
        }
    }
    __syncthreads();   // publishes bias staging (H is wave-private; no other barriers)

    int chunk = 0;
    #pragma unroll 1
    for (int L = 0; L < 3; ++L) {
        int Loff = L * 256;
        // this layer's H fragments -> registers (own pairs only)
        short8 bfr0[8], bfr1[8];
        #pragma unroll
        for (int kk = 0; kk < 8; ++kk) {
            bfr0[kk] = *(const short8*)(Hb + (size_t)((w2_ + 0) * 8 + kk) * 1024 + l * 16);
            bfr1[kk] = *(const short8*)(Hb + (size_t)((w2_ + 1) * 8 + kk) * 1024 + l * 16);
        }
        #pragma unroll 1
        for (int tt2 = 0; tt2 < 8; ++tt2) {
            int tt = tt2 * 2;
            TT_BODY(wA, wB)
            tt = tt2 * 2 + 1;
            TT_BODY(wB, wA)
        }
    }
}

// ---------------- kernel 4: f-MLP + sigmoid + MSE loss ----------------
// grid = 300 blocks x 2 cells, 256 threads.
__global__ void k4_f(const float* __restrict__ xf,
                     const float* __restrict__ fw1, const float* __restrict__ fb1,
                     const float* __restrict__ fw2, const float* __restrict__ fb2,
                     const float* __restrict__ fw3, const float* __restrict__ fb3,
                     const float* __restrict__ fw4, const float* __restrict__ fb4,
                     const int* __restrict__ sy, const int* __restrict__ qy,
                     float* __restrict__ out) {
    __shared__ float xb[2][256], yb[2][256], y3[2][32];
    int base = blockIdx.x * 2;
    int t = threadIdx.x;
    #pragma unroll
    for (int cc = 0; cc < 2; ++cc) {
        const float* xr = xf + (size_t)(base + cc) * 2048 + t;
        float s = 0.f;
        #pragma unroll
        for (int s8 = 0; s8 < 8; ++s8) s += xr[s8 * 256];
        xb[cc][t] = s;
    }
    __syncthreads();
    float acc[2];
    acc[0] = fb1[t]; acc[1] = fb1[t];
    #pragma unroll 4
    for (int k = 0; k < 256; ++k) {
        float wv = fw1[(size_t)k * 256 + t];
        acc[0] += xb[0][k] * wv;
        acc[1] += xb[1][k] * wv;
    }
    yb[0][t] = acc[0] > 0.f ? acc[0] : 0.f;
    yb[1][t] = acc[1] > 0.f ? acc[1] : 0.f;
    __syncthreads();
    acc[0] = fb2[t]; acc[1] = fb2[t];
    #pragma unroll 4
    for (int k = 0; k < 256; ++k) {
        float wv = fw2[(size_t)k * 256 + t];
        acc[0] += yb[0][k] * wv;
        acc[1] += yb[1][k] * wv;
    }
    xb[0][t] = acc[0] > 0.f ? acc[0] : 0.f;
    xb[1][t] = acc[1] > 0.f ? acc[1] : 0.f;
    __syncthreads();
    if (t < 58) {
        int cc = t / 29, col = t % 29;
        float a = fb3[col];
        #pragma unroll 4
        for (int k = 0; k < 256; ++k) a += xb[cc][k] * fw3[(size_t)k * 29 + col];
        y3[cc][col] = a > 0.f ? a : 0.f;
    }
    __syncthreads();
    if (t < 2) {
        int cc = t;
        float z = fb4[0];
        for (int k = 0; k < 29; ++k) z += y3[cc][k] * fw4[k];
        float score = 1.0f / (1.0f + __expf(-z));
        int bqs = base + cc;
        int b = bqs / 75, rem = bqs % 75, qi = rem / 5, si = rem % 5;
        float label = (sy[b * NS + si] == qy[b * NQ + qi]) ? 1.0f : 0.0f;
        float d = label - score;
        atomicAdd(out, d * d * 0.125f);
    }
}

// ---------------- launch ----------------
extern "C" void kernel_launch(void* const* d_in, const int* in_sizes, int n_in,
                              void* d_out, int out_size, void* d_ws, size_t ws_size,
                              hipStream_t stream) {
    const float* sup = (const float*)d_in[0];
    const float* qry = (const float*)d_in[1];
    const int*   sy  = (const int*)d_in[2];
    const int*   qy  = (const int*)d_in[3];
    const float* gw1 = (const float*)d_in[4];
    const float* gb1 = (const float*)d_in[5];
    const float* gw2 = (const float*)d_in[6];
    const float* gb2 = (const float*)d_in[7];
    const float* gw3 = (const float*)d_in[8];
    const float* gb3 = (const float*)d_in[9];
    const float* gw4 = (const float*)d_in[10];
    const float* gb4 = (const float*)d_in[11];
    const float* fw1 = (const float*)d_in[12];
    const float* fb1 = (const float*)d_in[13];
    const float* fw2 = (const float*)d_in[14];
    const float* fb2 = (const float*)d_in[15];
    const float* fw3 = (const float*)d_in[16];
    const float* fb3 = (const float*)d_in[17];
    const float* fw4 = (const float*)d_in[18];
    const float* fb4 = (const float*)d_in[19];

    float* ws = (float*)d_ws;
    float* A  = ws + A_OFF_F;
    float* B  = ws + B_OFF_F;
    float* xf = ws + XF_OFF_F;
    unsigned short* wf = (unsigned short*)((char*)d_ws + WF_OFF_BYTES);
    float* out = (float*)d_out;

    hipMemsetAsync(out, 0, sizeof(float), stream);

    k12<<<688, 512, 0, stream>>>(sup, qry, gw1, gb1, gw2, gw3, gw4, ws, wf);
    k3_g<<<600, 512, 0, stream>>>(A, B, wf, gb2, gb3, gb4, xf);
    k4_f<<<300, 256, 0, stream>>>(xf, fw1, fb1, fw2, fb2, fw3, fb3, fw4, fb4, sy, qy, out);
}

// Round 8
// 183.840 us; speedup vs baseline: 1.0994x; 1.0994x over previous
//
#include <hip/hip_runtime.h>

// ---------------- types / helpers ----------------
typedef __attribute__((ext_vector_type(8))) __bf16 bf16x8;
typedef __attribute__((ext_vector_type(8))) short short8;
typedef __attribute__((ext_vector_type(4))) float f32x4;
typedef unsigned int u32;

static __device__ __forceinline__ unsigned short f2bf(float f) {
    u32 u = __float_as_uint(f);
    u += 0x7FFFu + ((u >> 16) & 1u);
    return (unsigned short)(u >> 16);
}
static __device__ __forceinline__ u32 cvt_pk_bf16(float lo, float hi) {
    u32 r;
    asm("v_cvt_pk_bf16_f32 %0, %1, %2" : "=v"(r) : "v"(lo), "v"(hi));
    return r;
}
static __device__ __forceinline__ bf16x8 as_bf16x8(short8 v) {
    return __builtin_bit_cast(bf16x8, v);
}
static __device__ __forceinline__ f32x4 mfma16(short8 a, short8 b, f32x4 c) {
    return __builtin_amdgcn_mfma_f32_16x16x32_bf16(as_bf16x8(a), as_bf16x8(b), c, 0, 0, 0);
}

// problem sizes
#define NB 8
#define NS 5
#define NQ 15
// ws layout (floats)
#define A_OFF_F 0
#define B_OFF_F (640*256)                        // 163840
#define XF_OFF_F (B_OFF_F + 1920*256)            // 655360
#define WF_OFF_BYTES ((XF_OFF_F + 600*256)*4)    // 3235840, 16B aligned

// ---------------- kernel 1+2 fused ----------------
// blocks 0..639: k1 (A = sup@W1a + b1, B = qry@W1b), 512 thr, (cell, 64-col grp)
// blocks 640..687: k2 (g_w2/3/4 -> bf16 A-frag chunks), 512 thr, one 8KB chunk each.
// wf chunk cid = L*16+tt at byte cid*8192; within: kk*1024 + lane*16; lane l holds
// W[k = kk*32+(l>>4)*8+j][outcol = tt*16+(l&15)], j=0..7 (bf16).
__global__ void k12(const float* __restrict__ sup, const float* __restrict__ qry,
                    const float* __restrict__ gw1, const float* __restrict__ gb1,
                    const float* __restrict__ w2, const float* __restrict__ w3,
                    const float* __restrict__ w4,
                    float* __restrict__ ws, unsigned short* __restrict__ wfout) {
    __shared__ float x[258 * 16];
    int bid = blockIdx.x;
    int t = threadIdx.x;
    if (bid >= 640) {
        int cid = bid - 640;          // 0..47
        int L = cid >> 4, tt = cid & 15;
        int kk = t >> 6, l = t & 63;
        const float* W = (L == 0) ? w2 : ((L == 1) ? w3 : w4);
        int nn = tt * 16 + (l & 15);
        int k0 = kk * 32 + (l >> 4) * 8;
        short8 ov;
        #pragma unroll
        for (int j = 0; j < 8; ++j)
            ov[j] = (short)f2bf(W[(size_t)(k0 + j) * 256 + nn]);
        *(short8*)((char*)wfout + (size_t)cid * 8192 + kk * 1024 + l * 16) = ov;
        return;
    }
    int cg = bid & 3;
    int cid = bid >> 2;
    bool isA = (cid < NB * NS);
    int cell = isA ? cid : (cid - NB * NS);
    const float* src = (isA ? sup : qry) + (size_t)cell * 4096;
    ((float4*)x)[t] = ((const float4*)src)[t];
    ((float4*)x)[t + 512] = ((const float4*)src)[t + 512];
    if (t < 16) {
        x[256 * 16 + t] = (float)(t >> 2) * 0.25f;
        x[257 * 16 + t] = (float)(t & 3) * 0.25f;
    }
    __syncthreads();
    int col = cg * 64 + (t & 63);
    int ng = t >> 6;
    float binit = isA ? gb1[col] : 0.0f;
    float ax = binit, ay = binit;
    int koff = isA ? 0 : 258;
    #pragma unroll 4
    for (int k = 0; k < 258; ++k) {
        float wv = gw1[(size_t)(koff + k) * 256 + col];
        float2 xv = *(const float2*)(x + k * 16 + ng * 2);
        ax += xv.x * wv;
        ay += xv.y * wv;
    }
    float* dst = ws + (isA ? A_OFF_F : B_OFF_F) + ((size_t)cell * 16 + ng * 2) * 256 + col;
    dst[0] = ax;
    dst[256] = ay;
}

// ---------------- kernel 3: g-MLP layers 2..4 + pair-sum (N-split waves) ----------------
// grid = 600 blocks (one cell = 256 pairs), 512 threads = 8 waves.
// Wave w owns OUTCOLS [w*32, w*32+32) (chunks 2w, 2w+1) for ALL 256 pairs:
//   - W: 2 chunks (16KB) in regs, loaded once per layer (no redundant streaming)
//   - H: LDS 128KB B-frag layout, each frag read once per layer per wave
//   - layer output of wave w == frag column kk'=w of next layer's H -> in-place scatter
//   - acc[16 pg][2 tti] f32x4 = 128 VGPRs
// Barriers: 1 (phase1) + 2 per inner layer = 5 total.
__launch_bounds__(512, 2)
__global__ void k3_g(const float* __restrict__ wsA, const float* __restrict__ wsB,
                     const unsigned short* __restrict__ wf,
                     const float* __restrict__ gb2, const float* __restrict__ gb3,
                     const float* __restrict__ gb4, float* __restrict__ xf) {
    __shared__ short Hf[65536];   // 128 KB: frag(m,kk) at (m*8+kk)*1024 bytes
    __shared__ float bs[768];
    int bqs = blockIdx.x;
    int b = bqs / 75, rem = bqs % 75, qi = rem / 5, si = rem % 5;
    int t = threadIdx.x;
    int w = t >> 6, l = t & 63;
    int g = l >> 4, c = l & 15;
    char* Hb = (char*)Hf;
    const char* wfb = (const char*)wf;

    if (t < 256) { bs[t] = gb2[t]; bs[256 + t] = gb3[t]; bs[512 + t] = gb4[t]; }

    // layer-0 W chunks (2w, 2w+1) -> regs (lands under phase 1)
    short8 wA[8], wB[8];
    {
        const char* wsrc = wfb + (size_t)(2 * w) * 8192 + l * 16;
        #pragma unroll
        for (int kk = 0; kk < 8; ++kk) wA[kk] = *(const short8*)(wsrc + kk * 1024);
        #pragma unroll
        for (int kk = 0; kk < 8; ++kk) wB[kk] = *(const short8*)(wsrc + 8192 + kk * 1024);
    }

    // ---- phase 1: H1[pair][k] = relu(A[n][k] + B[m][k]) -> bf16 B-frag layout.
    // pair = m*16 + c (m = 2w+pg, n = c); k = kk*32 + g*8 + j.
    {
        const float* Arow = wsA + (size_t)(b * NS + si) * 4096 + c * 256;
        const float* Brow = wsB + (size_t)(b * NQ + qi) * 4096;
        #pragma unroll
        for (int pg = 0; pg < 2; ++pg) {
            int m = 2 * w + pg;
            #pragma unroll
            for (int kk = 0; kk < 8; ++kk) {
                const float* ap = Arow + kk * 32 + g * 8;
                const float* bp = Brow + m * 256 + kk * 32 + g * 8;
                float4 a0 = *(const float4*)ap, a1 = *(const float4*)(ap + 4);
                float4 b0 = *(const float4*)bp, b1 = *(const float4*)(bp + 4);
                uint4 hv;
                hv.x = cvt_pk_bf16(fmaxf(a0.x + b0.x, 0.f), fmaxf(a0.y + b0.y, 0.f));
                hv.y = cvt_pk_bf16(fmaxf(a0.z + b0.z, 0.f), fmaxf(a0.w + b0.w, 0.f));
                hv.z = cvt_pk_bf16(fmaxf(a1.x + b1.x, 0.f), fmaxf(a1.y + b1.y, 0.f));
                hv.w = cvt_pk_bf16(fmaxf(a1.z + b1.z, 0.f), fmaxf(a1.w + b1.w, 0.f));
                *(uint4*)(Hb + (size_t)(m * 8 + kk) * 1024 + l * 16) = hv;
            }
        }
    }
    __syncthreads();   // H1 complete + biases staged

    #pragma unroll 1
    for (int L = 0; L < 3; ++L) {
        // ---- MFMA: acc[pg][tti] covers outcols (2w+tti)*16+g*4+r, pairs pg*16+c
        f32x4 acc[16][2];
        #pragma unroll
        for (int pg = 0; pg < 16; ++pg) {
            acc[pg][0] = (f32x4){0.f, 0.f, 0.f, 0.f};
            acc[pg][1] = (f32x4){0.f, 0.f, 0.f, 0.f};
        }
        #pragma unroll
        for (int kk = 0; kk < 8; ++kk) {
            #pragma unroll
            for (int pg = 0; pg < 16; ++pg) {
                short8 h = *(const short8*)(Hb + (size_t)(pg * 8 + kk) * 1024 + l * 16);
                acc[pg][0] = mfma16(wA[kk], h, acc[pg][0]);
                acc[pg][1] = mfma16(wB[kk], h, acc[pg][1]);
            }
        }

        float4 bv0 = *(const float4*)(bs + L * 256 + (2 * w) * 16 + g * 4);
        float4 bv1 = *(const float4*)(bs + L * 256 + (2 * w + 1) * 16 + g * 4);

        if (L < 2) {
            // pack relu(acc+bias) -> bf16 words destined for frag column kk'=w
            u32 pk[16][2][2];
            #pragma unroll
            for (int pg = 0; pg < 16; ++pg) {
                pk[pg][0][0] = cvt_pk_bf16(fmaxf(acc[pg][0][0] + bv0.x, 0.f),
                                           fmaxf(acc[pg][0][1] + bv0.y, 0.f));
                pk[pg][0][1] = cvt_pk_bf16(fmaxf(acc[pg][0][2] + bv0.z, 0.f),
                                           fmaxf(acc[pg][0][3] + bv0.w, 0.f));
                pk[pg][1][0] = cvt_pk_bf16(fmaxf(acc[pg][1][0] + bv1.x, 0.f),
                                           fmaxf(acc[pg][1][1] + bv1.y, 0.f));
                pk[pg][1][1] = cvt_pk_bf16(fmaxf(acc[pg][1][2] + bv1.z, 0.f),
                                           fmaxf(acc[pg][1][3] + bv1.w, 0.f));
            }
            // prefetch next layer's W chunks (hidden behind barriers + scatter)
            {
                const char* ns = wfb + (size_t)((L + 1) * 16 + 2 * w) * 8192 + l * 16;
                #pragma unroll
                for (int kk = 0; kk < 8; ++kk) wA[kk] = *(const short8*)(ns + kk * 1024);
                #pragma unroll
                for (int kk = 0; kk < 8; ++kk) wB[kk] = *(const short8*)(ns + 8192 + kk * 1024);
            }
            __syncthreads();   // all H reads of layer L done
            // scatter: value(outcol, pair) -> frag(pg, w), lane (tti*2+(g>>1))*16+c,
            // byte (g&1)*8 + 4*h2.  addr = (pg*8+w)*1024 + tti*512 + (g>>1)*256 + c*16 + (g&1)*8
            {
                char* wbase = Hb + (size_t)w * 1024 + (g >> 1) * 256 + c * 16 + (g & 1) * 8;
                #pragma unroll
                for (int pg = 0; pg < 16; ++pg) {
                    uint2 q0 = {pk[pg][0][0], pk[pg][0][1]};
                    uint2 q1 = {pk[pg][1][0], pk[pg][1][1]};
                    *(uint2*)(wbase + (size_t)pg * 8192) = q0;
                    *(uint2*)(wbase + (size_t)pg * 8192 + 512) = q1;
                }
            }
            __syncthreads();   // next layer's H published
        } else {
            // final layer: relu + sum over all 256 pairs (16 pg in-reg, 16 c via shfl)
            float s00 = 0.f, s01 = 0.f, s02 = 0.f, s03 = 0.f;
            float s10 = 0.f, s11 = 0.f, s12 = 0.f, s13 = 0.f;
            #pragma unroll
            for (int pg = 0; pg < 16; ++pg) {
                s00 += fmaxf(acc[pg][0][0] + bv0.x, 0.f);
                s01 += fmaxf(acc[pg][0][1] + bv0.y, 0.f);
                s02 += fmaxf(acc[pg][0][2] + bv0.z, 0.f);
                s03 += fmaxf(acc[pg][0][3] + bv0.w, 0.f);
                s10 += fmaxf(acc[pg][1][0] + bv1.x, 0.f);
                s11 += fmaxf(acc[pg][1][1] + bv1.y, 0.f);
                s12 += fmaxf(acc[pg][1][2] + bv1.z, 0.f);
                s13 += fmaxf(acc[pg][1][3] + bv1.w, 0.f);
            }
            #pragma unroll
            for (int d = 1; d < 16; d <<= 1) {
                s00 += __shfl_xor(s00, d); s01 += __shfl_xor(s01, d);
                s02 += __shfl_xor(s02, d); s03 += __shfl_xor(s03, d);
                s10 += __shfl_xor(s10, d); s11 += __shfl_xor(s11, d);
                s12 += __shfl_xor(s12, d); s13 += __shfl_xor(s13, d);
            }
            if (c == 0) {
                float4 o0 = {s00, s01, s02, s03};
                float4 o1 = {s10, s11, s12, s13};
                *(float4*)(xf + (size_t)bqs * 256 + (2 * w) * 16 + g * 4) = o0;
                *(float4*)(xf + (size_t)bqs * 256 + (2 * w + 1) * 16 + g * 4) = o1;
            }
        }
    }
}

// ---------------- kernel 4: f-MLP + sigmoid + MSE loss ----------------
// grid = 150 blocks x 4 cells, 256 threads; fw loads reused 4x.
__global__ void k4_f(const float* __restrict__ xf,
                     const float* __restrict__ fw1, const float* __restrict__ fb1,
                     const float* __restrict__ fw2, const float* __restrict__ fb2,
                     const float* __restrict__ fw3, const float* __restrict__ fb3,
                     const float* __restrict__ fw4, const float* __restrict__ fb4,
                     const int* __restrict__ sy, const int* __restrict__ qy,
                     float* __restrict__ out) {
    __shared__ float xb[4][256], yb[4][256], y3[4][32];
    int base = blockIdx.x * 4;
    int t = threadIdx.x;
    #pragma unroll
    for (int cc = 0; cc < 4; ++cc)
        xb[cc][t] = xf[(size_t)(base + cc) * 256 + t];
    __syncthreads();
    float acc[4];
    #pragma unroll
    for (int cc = 0; cc < 4; ++cc) acc[cc] = fb1[t];
    #pragma unroll 8
    for (int k = 0; k < 256; ++k) {
        float wv = fw1[(size_t)k * 256 + t];
        #pragma unroll
        for (int cc = 0; cc < 4; ++cc) acc[cc] += xb[cc][k] * wv;
    }
    #pragma unroll
    for (int cc = 0; cc < 4; ++cc) yb[cc][t] = acc[cc] > 0.f ? acc[cc] : 0.f;
    __syncthreads();
    #pragma unroll
    for (int cc = 0; cc < 4; ++cc) acc[cc] = fb2[t];
    #pragma unroll 8
    for (int k = 0; k < 256; ++k) {
        float wv = fw2[(size_t)k * 256 + t];
        #pragma unroll
        for (int cc = 0; cc < 4; ++cc) acc[cc] += yb[cc][k] * wv;
    }
    #pragma unroll
    for (int cc = 0; cc < 4; ++cc) xb[cc][t] = acc[cc] > 0.f ? acc[cc] : 0.f;
    __syncthreads();
    if (t < 116) {
        int cc = t / 29, col = t % 29;
        float a = fb3[col];
        #pragma unroll 8
        for (int k = 0; k < 256; ++k) a += xb[cc][k] * fw3[(size_t)k * 29 + col];
        y3[cc][col] = a > 0.f ? a : 0.f;
    }
    __syncthreads();
    if (t < 4) {
        int cc = t;
        float z = fb4[0];
        for (int k = 0; k < 29; ++k) z += y3[cc][k] * fw4[k];
        float score = 1.0f / (1.0f + __expf(-z));
        int bqs = base + cc;
        int b = bqs / 75, rem = bqs % 75, qi = rem / 5, si = rem % 5;
        float label = (sy[b * NS + si] == qy[b * NQ + qi]) ? 1.0f : 0.0f;
        float d = label - score;
        atomicAdd(out, d * d * 0.125f);
    }
}

// ---------------- launch ----------------
extern "C" void kernel_launch(void* const* d_in, const int* in_sizes, int n_in,
                              void* d_out, int out_size, void* d_ws, size_t ws_size,
                              hipStream_t stream) {
    const float* sup = (const float*)d_in[0];
    const float* qry = (const float*)d_in[1];
    const int*   sy  = (const int*)d_in[2];
    const int*   qy  = (const int*)d_in[3];
    const float* gw1 = (const float*)d_in[4];
    const float* gb1 = (const float*)d_in[5];
    const float* gw2 = (const float*)d_in[6];
    const float* gb2 = (const float*)d_in[7];
    const float* gw3 = (const float*)d_in[8];
    const float* gb3 = (const float*)d_in[9];
    const float* gw4 = (const float*)d_in[10];
    const float* gb4 = (const float*)d_in[11];
    const float* fw1 = (const float*)d_in[12];
    const float* fb1 = (const float*)d_in[13];
    const float* fw2 = (const float*)d_in[14];
    const float* fb2 = (const float*)d_in[15];
    const float* fw3 = (const float*)d_in[16];
    const float* fb3 = (const float*)d_in[17];
    const float* fw4 = (const float*)d_in[18];
    const float* fb4 = (const float*)d_in[19];

    float* ws = (float*)d_ws;
    float* A  = ws + A_OFF_F;
    float* B  = ws + B_OFF_F;
    float* xf = ws + XF_OFF_F;
    unsigned short* wf = (unsigned short*)((char*)d_ws + WF_OFF_BYTES);
    float* out = (float*)d_out;

    hipMemsetAsync(out, 0, sizeof(float), stream);

    k12<<<688, 512, 0, stream>>>(sup, qry, gw1, gb1, gw2, gw3, gw4, ws, wf);
    k3_g<<<600, 512, 0, stream>>>(A, B, wf, gb2, gb3, gb4, xf);
    k4_f<<<150, 256, 0, stream>>>(xf, fw1, fb1, fw2, fb2, fw3, fb3, fw4, fb4, sy, qy, out);
}

// Round 9
// 169.151 us; speedup vs baseline: 1.1948x; 1.0868x over previous
//
#include <hip/hip_runtime.h>

// ---------------- types / helpers ----------------
typedef __attribute__((ext_vector_type(8))) __bf16 bf16x8;
typedef __attribute__((ext_vector_type(8))) short short8;
typedef __attribute__((ext_vector_type(4))) float f32x4;
typedef unsigned int u32;

static __device__ __forceinline__ unsigned short f2bf(float f) {
    u32 u = __float_as_uint(f);
    u += 0x7FFFu + ((u >> 16) & 1u);
    return (unsigned short)(u >> 16);
}
static __device__ __forceinline__ u32 cvt_pk_bf16(float lo, float hi) {
    u32 r;
    asm("v_cvt_pk_bf16_f32 %0, %1, %2" : "=v"(r) : "v"(lo), "v"(hi));
    return r;
}
static __device__ __forceinline__ bf16x8 as_bf16x8(short8 v) {
    return __builtin_bit_cast(bf16x8, v);
}
static __device__ __forceinline__ f32x4 mfma16(short8 a, short8 b, f32x4 c) {
    return __builtin_amdgcn_mfma_f32_16x16x32_bf16(as_bf16x8(a), as_bf16x8(b), c, 0, 0, 0);
}

// problem sizes
#define NB 8
#define NS 5
#define NQ 15
// ws layout (floats)
#define A_OFF_F 0
#define B_OFF_F (640*256)                        // 163840
#define XF_OFF_F (B_OFF_F + 1920*256)            // 655360
#define WF_OFF_BYTES ((XF_OFF_F + 600*256)*4)    // 3235840, 16B aligned

// ---------------- kernel 1+2 fused ----------------
// blocks 0..639: k1 (A = sup@W1a + b1, B = qry@W1b), 512 thr, (cell, 64-col grp)
// blocks 640..687: k2 (g_w2/3/4 -> bf16 A-frag chunks), 512 thr, one 8KB chunk each.
// wf chunk cid = L*16+tt at byte cid*8192; within: kk*1024 + lane*16; lane l holds
// W[k = kk*32+(l>>4)*8+j][outcol = tt*16+(l&15)], j=0..7 (bf16).
__global__ void k12(const float* __restrict__ sup, const float* __restrict__ qry,
                    const float* __restrict__ gw1, const float* __restrict__ gb1,
                    const float* __restrict__ w2, const float* __restrict__ w3,
                    const float* __restrict__ w4,
                    float* __restrict__ ws, unsigned short* __restrict__ wfout) {
    __shared__ float x[258 * 16];
    int bid = blockIdx.x;
    int t = threadIdx.x;
    if (bid >= 640) {
        int cid = bid - 640;          // 0..47
        int L = cid >> 4, tt = cid & 15;
        int kk = t >> 6, l = t & 63;
        const float* W = (L == 0) ? w2 : ((L == 1) ? w3 : w4);
        int nn = tt * 16 + (l & 15);
        int k0 = kk * 32 + (l >> 4) * 8;
        short8 ov;
        #pragma unroll
        for (int j = 0; j < 8; ++j)
            ov[j] = (short)f2bf(W[(size_t)(k0 + j) * 256 + nn]);
        *(short8*)((char*)wfout + (size_t)cid * 8192 + kk * 1024 + l * 16) = ov;
        return;
    }
    int cg = bid & 3;
    int cid = bid >> 2;
    bool isA = (cid < NB * NS);
    int cell = isA ? cid : (cid - NB * NS);
    const float* src = (isA ? sup : qry) + (size_t)cell * 4096;
    ((float4*)x)[t] = ((const float4*)src)[t];
    ((float4*)x)[t + 512] = ((const float4*)src)[t + 512];
    if (t < 16) {
        x[256 * 16 + t] = (float)(t >> 2) * 0.25f;
        x[257 * 16 + t] = (float)(t & 3) * 0.25f;
    }
    __syncthreads();
    int col = cg * 64 + (t & 63);
    int ng = t >> 6;
    float binit = isA ? gb1[col] : 0.0f;
    float ax = binit, ay = binit;
    int koff = isA ? 0 : 258;
    #pragma unroll 4
    for (int k = 0; k < 258; ++k) {
        float wv = gw1[(size_t)(koff + k) * 256 + col];
        float2 xv = *(const float2*)(x + k * 16 + ng * 2);
        ax += xv.x * wv;
        ay += xv.y * wv;
    }
    float* dst = ws + (isA ? A_OFF_F : B_OFF_F) + ((size_t)cell * 16 + ng * 2) * 256 + col;
    dst[0] = ax;
    dst[256] = ay;
}

// ---------------- kernel 3: g-MLP layers 2..4 + pair-sum (N-split waves) ----------------
// grid = 600 blocks (one cell = 256 pairs), 512 threads = 8 waves.
// Wave w owns OUTCOLS [w*32, w*32+32) (chunks 2w, 2w+1) for ALL 256 pairs:
//   - W: 2 chunks (16KB) in regs, loaded once per layer (no redundant streaming)
//   - H: LDS 128KB B-frag layout, each frag read once per layer per wave
//   - layer output of wave w == frag column kk'=w of next layer's H -> in-place scatter
//   - acc[16 pg][2 tti] f32x4 = 128 VGPRs
// launch_bounds (512,1): 256-VGPR cap. Live-across-barrier = acc(128)+wA/wB(64)+misc
// -> ~210 VGPR, no spill (round-8 spilled at the 128 cap). Occupancy is LDS-capped
// at 1 block/CU regardless.
__launch_bounds__(512, 1)
__global__ void k3_g(const float* __restrict__ wsA, const float* __restrict__ wsB,
                     const unsigned short* __restrict__ wf,
                     const float* __restrict__ gb2, const float* __restrict__ gb3,
                     const float* __restrict__ gb4, float* __restrict__ xf) {
    __shared__ short Hf[65536];   // 128 KB: frag(m,kk) at (m*8+kk)*1024 bytes
    __shared__ float bs[768];
    int bqs = blockIdx.x;
    int b = bqs / 75, rem = bqs % 75, qi = rem / 5, si = rem % 5;
    int t = threadIdx.x;
    int w = t >> 6, l = t & 63;
    int g = l >> 4, c = l & 15;
    char* Hb = (char*)Hf;
    const char* wfb = (const char*)wf;

    if (t < 256) { bs[t] = gb2[t]; bs[256 + t] = gb3[t]; bs[512 + t] = gb4[t]; }

    // layer-0 W chunks (2w, 2w+1) -> regs (lands under phase 1)
    short8 wA[8], wB[8];
    {
        const char* wsrc = wfb + (size_t)(2 * w) * 8192 + l * 16;
        #pragma unroll
        for (int kk = 0; kk < 8; ++kk) wA[kk] = *(const short8*)(wsrc + kk * 1024);
        #pragma unroll
        for (int kk = 0; kk < 8; ++kk) wB[kk] = *(const short8*)(wsrc + 8192 + kk * 1024);
    }

    // ---- phase 1: H1[pair][k] = relu(A[n][k] + B[m][k]) -> bf16 B-frag layout.
    // pair = m*16 + c (m = 2w+pg, n = c); k = kk*32 + g*8 + j.
    {
        const float* Arow = wsA + (size_t)(b * NS + si) * 4096 + c * 256;
        const float* Brow = wsB + (size_t)(b * NQ + qi) * 4096;
        #pragma unroll
        for (int pg = 0; pg < 2; ++pg) {
            int m = 2 * w + pg;
            #pragma unroll
            for (int kk = 0; kk < 8; ++kk) {
                const float* ap = Arow + kk * 32 + g * 8;
                const float* bp = Brow + m * 256 + kk * 32 + g * 8;
                float4 a0 = *(const float4*)ap, a1 = *(const float4*)(ap + 4);
                float4 b0 = *(const float4*)bp, b1 = *(const float4*)(bp + 4);
                uint4 hv;
                hv.x = cvt_pk_bf16(fmaxf(a0.x + b0.x, 0.f), fmaxf(a0.y + b0.y, 0.f));
                hv.y = cvt_pk_bf16(fmaxf(a0.z + b0.z, 0.f), fmaxf(a0.w + b0.w, 0.f));
                hv.z = cvt_pk_bf16(fmaxf(a1.x + b1.x, 0.f), fmaxf(a1.y + b1.y, 0.f));
                hv.w = cvt_pk_bf16(fmaxf(a1.z + b1.z, 0.f), fmaxf(a1.w + b1.w, 0.f));
                *(uint4*)(Hb + (size_t)(m * 8 + kk) * 1024 + l * 16) = hv;
            }
        }
    }
    __syncthreads();   // H1 complete + biases staged

    #pragma unroll 1
    for (int L = 0; L < 3; ++L) {
        // ---- MFMA: acc[pg][tti] covers outcols (2w+tti)*16+g*4+r, pairs pg*16+c
        f32x4 acc[16][2];
        #pragma unroll
        for (int pg = 0; pg < 16; ++pg) {
            acc[pg][0] = (f32x4){0.f, 0.f, 0.f, 0.f};
            acc[pg][1] = (f32x4){0.f, 0.f, 0.f, 0.f};
        }
        #pragma unroll
        for (int kk = 0; kk < 8; ++kk) {
            #pragma unroll
            for (int pg = 0; pg < 16; ++pg) {
                short8 h = *(const short8*)(Hb + (size_t)(pg * 8 + kk) * 1024 + l * 16);
                acc[pg][0] = mfma16(wA[kk], h, acc[pg][0]);
                acc[pg][1] = mfma16(wB[kk], h, acc[pg][1]);
            }
        }

        float4 bv0 = *(const float4*)(bs + L * 256 + (2 * w) * 16 + g * 4);
        float4 bv1 = *(const float4*)(bs + L * 256 + (2 * w + 1) * 16 + g * 4);

        if (L < 2) {
            // prefetch next layer's W chunks (in flight across the barrier + epilogue)
            {
                const char* ns = wfb + (size_t)((L + 1) * 16 + 2 * w) * 8192 + l * 16;
                #pragma unroll
                for (int kk = 0; kk < 8; ++kk) wA[kk] = *(const short8*)(ns + kk * 1024);
                #pragma unroll
                for (int kk = 0; kk < 8; ++kk) wB[kk] = *(const short8*)(ns + 8192 + kk * 1024);
            }
            __syncthreads();   // all H reads of layer L done
            // epilogue directly from acc (no held pk buffer): relu(acc+bias) -> bf16,
            // scatter to frag column kk'=w of next layer's H.
            // addr = (pg*8+w)*1024 + tti*512 + (g>>1)*256 + c*16 + (g&1)*8
            {
                char* wbase = Hb + (size_t)w * 1024 + (g >> 1) * 256 + c * 16 + (g & 1) * 8;
                #pragma unroll
                for (int pg = 0; pg < 16; ++pg) {
                    uint2 q0, q1;
                    q0.x = cvt_pk_bf16(fmaxf(acc[pg][0][0] + bv0.x, 0.f),
                                       fmaxf(acc[pg][0][1] + bv0.y, 0.f));
                    q0.y = cvt_pk_bf16(fmaxf(acc[pg][0][2] + bv0.z, 0.f),
                                       fmaxf(acc[pg][0][3] + bv0.w, 0.f));
                    q1.x = cvt_pk_bf16(fmaxf(acc[pg][1][0] + bv1.x, 0.f),
                                       fmaxf(acc[pg][1][1] + bv1.y, 0.f));
                    q1.y = cvt_pk_bf16(fmaxf(acc[pg][1][2] + bv1.z, 0.f),
                                       fmaxf(acc[pg][1][3] + bv1.w, 0.f));
                    *(uint2*)(wbase + (size_t)pg * 8192) = q0;
                    *(uint2*)(wbase + (size_t)pg * 8192 + 512) = q1;
                }
            }
            __syncthreads();   // next layer's H published
        } else {
            // final layer: relu + sum over all 256 pairs (16 pg in-reg, 16 c via shfl)
            float s00 = 0.f, s01 = 0.f, s02 = 0.f, s03 = 0.f;
            float s10 = 0.f, s11 = 0.f, s12 = 0.f, s13 = 0.f;
            #pragma unroll
            for (int pg = 0; pg < 16; ++pg) {
                s00 += fmaxf(acc[pg][0][0] + bv0.x, 0.f);
                s01 += fmaxf(acc[pg][0][1] + bv0.y, 0.f);
                s02 += fmaxf(acc[pg][0][2] + bv0.z, 0.f);
                s03 += fmaxf(acc[pg][0][3] + bv0.w, 0.f);
                s10 += fmaxf(acc[pg][1][0] + bv1.x, 0.f);
                s11 += fmaxf(acc[pg][1][1] + bv1.y, 0.f);
                s12 += fmaxf(acc[pg][1][2] + bv1.z, 0.f);
                s13 += fmaxf(acc[pg][1][3] + bv1.w, 0.f);
            }
            #pragma unroll
            for (int d = 1; d < 16; d <<= 1) {
                s00 += __shfl_xor(s00, d); s01 += __shfl_xor(s01, d);
                s02 += __shfl_xor(s02, d); s03 += __shfl_xor(s03, d);
                s10 += __shfl_xor(s10, d); s11 += __shfl_xor(s11, d);
                s12 += __shfl_xor(s12, d); s13 += __shfl_xor(s13, d);
            }
            if (c == 0) {
                float4 o0 = {s00, s01, s02, s03};
                float4 o1 = {s10, s11, s12, s13};
                *(float4*)(xf + (size_t)bqs * 256 + (2 * w) * 16 + g * 4) = o0;
                *(float4*)(xf + (size_t)bqs * 256 + (2 * w + 1) * 16 + g * 4) = o1;
            }
        }
    }
}

// ---------------- kernel 4: f-MLP + sigmoid + MSE loss ----------------
// grid = 150 blocks x 4 cells, 256 threads; fw loads reused 4x.
__global__ void k4_f(const float* __restrict__ xf,
                     const float* __restrict__ fw1, const float* __restrict__ fb1,
                     const float* __restrict__ fw2, const float* __restrict__ fb2,
                     const float* __restrict__ fw3, const float* __restrict__ fb3,
                     const float* __restrict__ fw4, const float* __restrict__ fb4,
                     const int* __restrict__ sy, const int* __restrict__ qy,
                     float* __restrict__ out) {
    __shared__ float xb[4][256], yb[4][256], y3[4][32];
    int base = blockIdx.x * 4;
    int t = threadIdx.x;
    #pragma unroll
    for (int cc = 0; cc < 4; ++cc)
        xb[cc][t] = xf[(size_t)(base + cc) * 256 + t];
    __syncthreads();
    float acc[4];
    #pragma unroll
    for (int cc = 0; cc < 4; ++cc) acc[cc] = fb1[t];
    #pragma unroll 8
    for (int k = 0; k < 256; ++k) {
        float wv = fw1[(size_t)k * 256 + t];
        #pragma unroll
        for (int cc = 0; cc < 4; ++cc) acc[cc] += xb[cc][k] * wv;
    }
    #pragma unroll
    for (int cc = 0; cc < 4; ++cc) yb[cc][t] = acc[cc] > 0.f ? acc[cc] : 0.f;
    __syncthreads();
    #pragma unroll
    for (int cc = 0; cc < 4; ++cc) acc[cc] = fb2[t];
    #pragma unroll 8
    for (int k = 0; k < 256; ++k) {
        float wv = fw2[(size_t)k * 256 + t];
        #pragma unroll
        for (int cc = 0; cc < 4; ++cc) acc[cc] += yb[cc][k] * wv;
    }
    #pragma unroll
    for (int cc = 0; cc < 4; ++cc) xb[cc][t] = acc[cc] > 0.f ? acc[cc] : 0.f;
    __syncthreads();
    if (t < 116) {
        int cc = t / 29, col = t % 29;
        float a = fb3[col];
        #pragma unroll 8
        for (int k = 0; k < 256; ++k) a += xb[cc][k] * fw3[(size_t)k * 29 + col];
        y3[cc][col] = a > 0.f ? a : 0.f;
    }
    __syncthreads();
    if (t < 4) {
        int cc = t;
        float z = fb4[0];
        for (int k = 0; k < 29; ++k) z += y3[cc][k] * fw4[k];
        float score = 1.0f / (1.0f + __expf(-z));
        int bqs = base + cc;
        int b = bqs / 75, rem = bqs % 75, qi = rem / 5, si = rem % 5;
        float label = (sy[b * NS + si] == qy[b * NQ + qi]) ? 1.0f : 0.0f;
        float d = label - score;
        atomicAdd(out, d * d * 0.125f);
    }
}

// ---------------- launch ----------------
extern "C" void kernel_launch(void* const* d_in, const int* in_sizes, int n_in,
                              void* d_out, int out_size, void* d_ws, size_t ws_size,
                              hipStream_t stream) {
    const float* sup = (const float*)d_in[0];
    const float* qry = (const float*)d_in[1];
    const int*   sy  = (const int*)d_in[2];
    const int*   qy  = (const int*)d_in[3];
    const float* gw1 = (const float*)d_in[4];
    const float* gb1 = (const float*)d_in[5];
    const float* gw2 = (const float*)d_in[6];
    const float* gb2 = (const float*)d_in[7];
    const float* gw3 = (const float*)d_in[8];
    const float* gb3 = (const float*)d_in[9];
    const float* gw4 = (const float*)d_in[10];
    const float* gb4 = (const float*)d_in[11];
    const float* fw1 = (const float*)d_in[12];
    const float* fb1 = (const float*)d_in[13];
    const float* fw2 = (const float*)d_in[14];
    const float* fb2 = (const float*)d_in[15];
    const float* fw3 = (const float*)d_in[16];
    const float* fb3 = (const float*)d_in[17];
    const float* fw4 = (const float*)d_in[18];
    const float* fb4 = (const float*)d_in[19];

    float* ws = (float*)d_ws;
    float* A  = ws + A_OFF_F;
    float* B  = ws + B_OFF_F;
    float* xf = ws + XF_OFF_F;
    unsigned short* wf = (unsigned short*)((char*)d_ws + WF_OFF_BYTES);
    float* out = (float*)d_out;

    hipMemsetAsync(out, 0, sizeof(float), stream);

    k12<<<688, 512, 0, stream>>>(sup, qry, gw1, gb1, gw2, gw3, gw4, ws, wf);
    k3_g<<<600, 512, 0, stream>>>(A, B, wf, gb2, gb3, gb4, xf);
    k4_f<<<150, 256, 0, stream>>>(xf, fw1, fb1, fw2, fb2, fw3, fb3, fw4, fb4, sy, qy, out);
}

// Round 10
// 162.861 us; speedup vs baseline: 1.2410x; 1.0386x over previous
//
#include <hip/hip_runtime.h>

// ---------------- types / helpers ----------------
typedef __attribute__((ext_vector_type(8))) __bf16 bf16x8;
typedef __attribute__((ext_vector_type(8))) short short8;
typedef __attribute__((ext_vector_type(4))) float f32x4;
typedef unsigned int u32;

static __device__ __forceinline__ unsigned short f2bf(float f) {
    u32 u = __float_as_uint(f);
    u += 0x7FFFu + ((u >> 16) & 1u);
    return (unsigned short)(u >> 16);
}
static __device__ __forceinline__ u32 cvt_pk_bf16(float lo, float hi) {
    u32 r;
    asm("v_cvt_pk_bf16_f32 %0, %1, %2" : "=v"(r) : "v"(lo), "v"(hi));
    return r;
}
static __device__ __forceinline__ bf16x8 as_bf16x8(short8 v) {
    return __builtin_bit_cast(bf16x8, v);
}
static __device__ __forceinline__ f32x4 mfma16(short8 a, short8 b, f32x4 c) {
    return __builtin_amdgcn_mfma_f32_16x16x32_bf16(as_bf16x8(a), as_bf16x8(b), c, 0, 0, 0);
}

// problem sizes
#define NB 8
#define NS 5
#define NQ 15
// ws layout (floats)
#define A_OFF_F 0
#define B_OFF_F (640*256)                        // 163840
#define XF_OFF_F (B_OFF_F + 1920*256)            // 655360
#define WF_OFF_BYTES ((XF_OFF_F + 600*512)*4)    // 3850240, 16B aligned

// ---------------- kernel 1+2 fused ----------------
// blocks 0..639: k1 (A = sup@W1a + b1, B = qry@W1b), 512 thr, (cell, 64-col grp)
// blocks 640..687: k2 (g_w2/3/4 -> bf16 A-frag chunks), 512 thr, one 8KB chunk each.
// wf chunk cid = L*16+tt at byte cid*8192; within: kk*1024 + lane*16; lane l holds
// W[k = kk*32+(l>>4)*8+j][outcol = tt*16+(l&15)], j=0..7 (bf16).
__global__ void k12(const float* __restrict__ sup, const float* __restrict__ qry,
                    const float* __restrict__ gw1, const float* __restrict__ gb1,
                    const float* __restrict__ w2, const float* __restrict__ w3,
                    const float* __restrict__ w4,
                    float* __restrict__ ws, unsigned short* __restrict__ wfout) {
    __shared__ float x[258 * 16];
    int bid = blockIdx.x;
    int t = threadIdx.x;
    if (bid >= 640) {
        int cid = bid - 640;          // 0..47
        int L = cid >> 4, tt = cid & 15;
        int kk = t >> 6, l = t & 63;
        const float* W = (L == 0) ? w2 : ((L == 1) ? w3 : w4);
        int nn = tt * 16 + (l & 15);
        int k0 = kk * 32 + (l >> 4) * 8;
        short8 ov;
        #pragma unroll
        for (int j = 0; j < 8; ++j)
            ov[j] = (short)f2bf(W[(size_t)(k0 + j) * 256 + nn]);
        *(short8*)((char*)wfout + (size_t)cid * 8192 + kk * 1024 + l * 16) = ov;
        return;
    }
    int cg = bid & 3;
    int cid = bid >> 2;
    bool isA = (cid < NB * NS);
    int cell = isA ? cid : (cid - NB * NS);
    const float* src = (isA ? sup : qry) + (size_t)cell * 4096;
    ((float4*)x)[t] = ((const float4*)src)[t];
    ((float4*)x)[t + 512] = ((const float4*)src)[t + 512];
    if (t < 16) {
        x[256 * 16 + t] = (float)(t >> 2) * 0.25f;
        x[257 * 16 + t] = (float)(t & 3) * 0.25f;
    }
    __syncthreads();
    int col = cg * 64 + (t & 63);
    int ng = t >> 6;
    float binit = isA ? gb1[col] : 0.0f;
    float ax = binit, ay = binit;
    int koff = isA ? 0 : 258;
    #pragma unroll 4
    for (int k = 0; k < 258; ++k) {
        float wv = gw1[(size_t)(koff + k) * 256 + col];
        float2 xv = *(const float2*)(x + k * 16 + ng * 2);
        ax += xv.x * wv;
        ay += xv.y * wv;
    }
    float* dst = ws + (isA ? A_OFF_F : B_OFF_F) + ((size_t)cell * 16 + ng * 2) * 256 + col;
    dst[0] = ax;
    dst[256] = ay;
}

// ---------------- kernel 3: g-MLP layers 2..4 + pair-sum (2x4 wave tiling) ----------------
// grid = 600 blocks (one cell = 256 pairs), 512 threads = 8 waves (wp x wn = 2 x 4).
// Wave (wp,wn): pairs [wp*128,+128), outcols [wn*64,+64).
//   - H: LDS 128KB B-frag layout; wave reads only its 8 pg frags -> 512KB/CU/layer
//   - W: streamed per-kk from L2 (4x1KB frags, 1-step dbuf, 32 rolling regs)
//     -> 256KB/CU/layer; both pipes < MFMA (9.9k cyc) -> MFMA-bound
//   - acc[8 pg][4 tti] f32x4 = 128 regs
__launch_bounds__(512, 1)
__global__ void k3_g(const float* __restrict__ wsA, const float* __restrict__ wsB,
                     const unsigned short* __restrict__ wf,
                     const float* __restrict__ gb2, const float* __restrict__ gb3,
                     const float* __restrict__ gb4, float* __restrict__ xf) {
    __shared__ short Hf[65536];   // 128 KB: frag(m,kk) at (m*8+kk)*1024 bytes
    __shared__ float bs[768];
    int bqs = blockIdx.x;
    int b = bqs / 75, rem = bqs % 75, qi = rem / 5, si = rem % 5;
    int t = threadIdx.x;
    int w = t >> 6, l = t & 63;
    int g = l >> 4, c = l & 15;
    int wp = w >> 2, wn = w & 3;
    char* Hb = (char*)Hf;
    const char* wfb = (const char*)wf;

    if (t < 256) { bs[t] = gb2[t]; bs[256 + t] = gb3[t]; bs[512 + t] = gb4[t]; }

    // W step (L=0,kk=0) -> wcur (lands under phase 1)
    short8 wcur[4];
    #pragma unroll
    for (int tti = 0; tti < 4; ++tti)
        wcur[tti] = *(const short8*)(wfb + (size_t)(wn * 4 + tti) * 8192 + l * 16);

    // ---- phase 1: H1[pair][k] = relu(A[n][k] + B[m][k]) -> bf16 B-frag layout.
    // pair = m*16 + c (m = 2w+pg, n = c); k = kk*32 + g*8 + j.
    {
        const float* Arow = wsA + (size_t)(b * NS + si) * 4096 + c * 256;
        const float* Brow = wsB + (size_t)(b * NQ + qi) * 4096;
        #pragma unroll
        for (int pg = 0; pg < 2; ++pg) {
            int m = 2 * w + pg;
            #pragma unroll
            for (int kk = 0; kk < 8; ++kk) {
                const float* ap = Arow + kk * 32 + g * 8;
                const float* bp = Brow + m * 256 + kk * 32 + g * 8;
                float4 a0 = *(const float4*)ap, a1 = *(const float4*)(ap + 4);
                float4 b0 = *(const float4*)bp, b1 = *(const float4*)(bp + 4);
                uint4 hv;
                hv.x = cvt_pk_bf16(fmaxf(a0.x + b0.x, 0.f), fmaxf(a0.y + b0.y, 0.f));
                hv.y = cvt_pk_bf16(fmaxf(a0.z + b0.z, 0.f), fmaxf(a0.w + b0.w, 0.f));
                hv.z = cvt_pk_bf16(fmaxf(a1.x + b1.x, 0.f), fmaxf(a1.y + b1.y, 0.f));
                hv.w = cvt_pk_bf16(fmaxf(a1.z + b1.z, 0.f), fmaxf(a1.w + b1.w, 0.f));
                *(uint4*)(Hb + (size_t)(m * 8 + kk) * 1024 + l * 16) = hv;
            }
        }
    }
    __syncthreads();   // H1 complete + biases staged

    #pragma unroll 1
    for (int L = 0; L < 3; ++L) {
        f32x4 acc[8][4];
        #pragma unroll
        for (int pg = 0; pg < 8; ++pg)
            #pragma unroll
            for (int tti = 0; tti < 4; ++tti)
                acc[pg][tti] = (f32x4){0.f, 0.f, 0.f, 0.f};

        #pragma unroll
        for (int kk = 0; kk < 8; ++kk) {
            // prefetch next W step (stays in flight under this step's MFMAs)
            int s = L * 8 + kk + 1; if (s > 23) s = 23;
            int Ln = s >> 3, kn = s & 7;
            short8 wnxt[4];
            #pragma unroll
            for (int tti = 0; tti < 4; ++tti)
                wnxt[tti] = *(const short8*)(wfb +
                    (size_t)(Ln * 16 + wn * 4 + tti) * 8192 + kn * 1024 + l * 16);
            #pragma unroll
            for (int pg = 0; pg < 8; ++pg) {
                short8 h = *(const short8*)(Hb +
                    (size_t)((wp * 8 + pg) * 8 + kk) * 1024 + l * 16);
                #pragma unroll
                for (int tti = 0; tti < 4; ++tti)
                    acc[pg][tti] = mfma16(wcur[tti], h, acc[pg][tti]);
            }
            #pragma unroll
            for (int tti = 0; tti < 4; ++tti) wcur[tti] = wnxt[tti];
        }

        float4 bv[4];
        #pragma unroll
        for (int tti = 0; tti < 4; ++tti)
            bv[tti] = *(const float4*)(bs + L * 256 + wn * 64 + tti * 16 + g * 4);

        if (L < 2) {
            __syncthreads();   // all H reads of layer L done
            // scatter relu(acc+bias) -> next-layer frags:
            // m = wp*8+pg; kk' = wn*2+(tti>>1); dlane = ((tti&1)*2+(g>>1))*16 + c;
            // byte = (g&1)*8
            #pragma unroll
            for (int pg = 0; pg < 8; ++pg) {
                int m = wp * 8 + pg;
                #pragma unroll
                for (int tti = 0; tti < 4; ++tti) {
                    uint2 q;
                    q.x = cvt_pk_bf16(fmaxf(acc[pg][tti][0] + bv[tti].x, 0.f),
                                      fmaxf(acc[pg][tti][1] + bv[tti].y, 0.f));
                    q.y = cvt_pk_bf16(fmaxf(acc[pg][tti][2] + bv[tti].z, 0.f),
                                      fmaxf(acc[pg][tti][3] + bv[tti].w, 0.f));
                    int kk2 = wn * 2 + (tti >> 1);
                    int dlane = ((tti & 1) * 2 + (g >> 1)) * 16 + c;
                    *(uint2*)(Hb + (size_t)(m * 8 + kk2) * 1024 + dlane * 16 + (g & 1) * 8) = q;
                }
            }
            __syncthreads();   // next layer's H published
        } else {
            // final layer: relu + sum over this wave's 128 pairs (8 pg in-reg, 16 c shfl)
            #pragma unroll
            for (int tti = 0; tti < 4; ++tti) {
                float s0 = 0.f, s1 = 0.f, s2 = 0.f, s3 = 0.f;
                #pragma unroll
                for (int pg = 0; pg < 8; ++pg) {
                    s0 += fmaxf(acc[pg][tti][0] + bv[tti].x, 0.f);
                    s1 += fmaxf(acc[pg][tti][1] + bv[tti].y, 0.f);
                    s2 += fmaxf(acc[pg][tti][2] + bv[tti].z, 0.f);
                    s3 += fmaxf(acc[pg][tti][3] + bv[tti].w, 0.f);
                }
                #pragma unroll
                for (int d = 1; d < 16; d <<= 1) {
                    s0 += __shfl_xor(s0, d); s1 += __shfl_xor(s1, d);
                    s2 += __shfl_xor(s2, d); s3 += __shfl_xor(s3, d);
                }
                if (c == 0) {
                    float4 o = {s0, s1, s2, s3};
                    *(float4*)(xf + ((size_t)bqs * 2 + wp) * 256 +
                               wn * 64 + tti * 16 + g * 4) = o;
                }
            }
        }
    }
}

// ---------------- kernel 4: f-MLP + sigmoid + MSE loss ----------------
// grid = 150 blocks x 4 cells, 256 threads; fw loads reused 4x.
__global__ void k4_f(const float* __restrict__ xf,
                     const float* __restrict__ fw1, const float* __restrict__ fb1,
                     const float* __restrict__ fw2, const float* __restrict__ fb2,
                     const float* __restrict__ fw3, const float* __restrict__ fb3,
                     const float* __restrict__ fw4, const float* __restrict__ fb4,
                     const int* __restrict__ sy, const int* __restrict__ qy,
                     float* __restrict__ out) {
    __shared__ float xb[4][256], yb[4][256], y3[4][32];
    int base = blockIdx.x * 4;
    int t = threadIdx.x;
    #pragma unroll
    for (int cc = 0; cc < 4; ++cc) {
        const float* xr = xf + (size_t)(base + cc) * 512 + t;
        xb[cc][t] = xr[0] + xr[256];
    }
    __syncthreads();
    float acc[4];
    #pragma unroll
    for (int cc = 0; cc < 4; ++cc) acc[cc] = fb1[t];
    #pragma unroll 8
    for (int k = 0; k < 256; ++k) {
        float wv = fw1[(size_t)k * 256 + t];
        #pragma unroll
        for (int cc = 0; cc < 4; ++cc) acc[cc] += xb[cc][k] * wv;
    }
    #pragma unroll
    for (int cc = 0; cc < 4; ++cc) yb[cc][t] = acc[cc] > 0.f ? acc[cc] : 0.f;
    __syncthreads();
    #pragma unroll
    for (int cc = 0; cc < 4; ++cc) acc[cc] = fb2[t];
    #pragma unroll 8
    for (int k = 0; k < 256; ++k) {
        float wv = fw2[(size_t)k * 256 + t];
        #pragma unroll
        for (int cc = 0; cc < 4; ++cc) acc[cc] += yb[cc][k] * wv;
    }
    #pragma unroll
    for (int cc = 0; cc < 4; ++cc) xb[cc][t] = acc[cc] > 0.f ? acc[cc] : 0.f;
    __syncthreads();
    if (t < 116) {
        int cc = t / 29, col = t % 29;
        float a = fb3[col];
        #pragma unroll 8
        for (int k = 0; k < 256; ++k) a += xb[cc][k] * fw3[(size_t)k * 29 + col];
        y3[cc][col] = a > 0.f ? a : 0.f;
    }
    __syncthreads();
    if (t < 4) {
        int cc = t;
        float z = fb4[0];
        for (int k = 0; k < 29; ++k) z += y3[cc][k] * fw4[k];
        float score = 1.0f / (1.0f + __expf(-z));
        int bqs = base + cc;
        int b = bqs / 75, rem = bqs % 75, qi = rem / 5, si = rem % 5;
        float label = (sy[b * NS + si] == qy[b * NQ + qi]) ? 1.0f : 0.0f;
        float d = label - score;
        atomicAdd(out, d * d * 0.125f);
    }
}

// ---------------- launch ----------------
extern "C" void kernel_launch(void* const* d_in, const int* in_sizes, int n_in,
                              void* d_out, int out_size, void* d_ws, size_t ws_size,
                              hipStream_t stream) {
    const float* sup = (const float*)d_in[0];
    const float* qry = (const float*)d_in[1];
    const int*   sy  = (const int*)d_in[2];
    const int*   qy  = (const int*)d_in[3];
    const float* gw1 = (const float*)d_in[4];
    const float* gb1 = (const float*)d_in[5];
    const float* gw2 = (const float*)d_in[6];
    const float* gb2 = (const float*)d_in[7];
    const float* gw3 = (const float*)d_in[8];
    const float* gb3 = (const float*)d_in[9];
    const float* gw4 = (const float*)d_in[10];
    const float* gb4 = (const float*)d_in[11];
    const float* fw1 = (const float*)d_in[12];
    const float* fb1 = (const float*)d_in[13];
    const float* fw2 = (const float*)d_in[14];
    const float* fb2 = (const float*)d_in[15];
    const float* fw3 = (const float*)d_in[16];
    const float* fb3 = (const float*)d_in[17];
    const float* fw4 = (const float*)d_in[18];
    const float* fb4 = (const float*)d_in[19];

    float* ws = (float*)d_ws;
    float* A  = ws + A_OFF_F;
    float* B  = ws + B_OFF_F;
    float* xf = ws + XF_OFF_F;
    unsigned short* wf = (unsigned short*)((char*)d_ws + WF_OFF_BYTES);
    float* out = (float*)d_out;

    hipMemsetAsync(out, 0, sizeof(float), stream);

    k12<<<688, 512, 0, stream>>>(sup, qry, gw1, gb1, gw2, gw3, gw4, ws, wf);
    k3_g<<<600, 512, 0, stream>>>(A, B, wf, gb2, gb3, gb4, xf);
    k4_f<<<150, 256, 0, stream>>>(xf, fw1, fb1, fw2, fb2, fw3, fb3, fw4, fb4, sy, qy, out);
}

// Round 11
// 152.393 us; speedup vs baseline: 1.3262x; 1.0687x over previous
//
#include <hip/hip_runtime.h>

// ---------------- types / helpers ----------------
typedef __attribute__((ext_vector_type(8))) __bf16 bf16x8;
typedef __attribute__((ext_vector_type(8))) short short8;
typedef __attribute__((ext_vector_type(4))) float f32x4;
typedef unsigned int u32;

static __device__ __forceinline__ unsigned short f2bf(float f) {
    u32 u = __float_as_uint(f);
    u += 0x7FFFu + ((u >> 16) & 1u);
    return (unsigned short)(u >> 16);
}
static __device__ __forceinline__ u32 cvt_pk_bf16(float lo, float hi) {
    u32 r;
    asm("v_cvt_pk_bf16_f32 %0, %1, %2" : "=v"(r) : "v"(lo), "v"(hi));
    return r;
}
static __device__ __forceinline__ bf16x8 as_bf16x8(short8 v) {
    return __builtin_bit_cast(bf16x8, v);
}
static __device__ __forceinline__ f32x4 mfma16(short8 a, short8 b, f32x4 c) {
    return __builtin_amdgcn_mfma_f32_16x16x32_bf16(as_bf16x8(a), as_bf16x8(b), c, 0, 0, 0);
}

// problem sizes
#define NB 8
#define NS 5
#define NQ 15
// ws layout (floats)
#define A_OFF_F 0
#define B_OFF_F (640*256)                        // 163840
#define XF_OFF_F (B_OFF_F + 1920*256)            // 655360
#define WF_OFF_BYTES ((XF_OFF_F + 600*1024)*4)   // 5079040, 16B aligned

// ---------------- kernel 1+2 fused ----------------
// blocks 0..639: k1 (A = sup@W1a + b1, B = qry@W1b), 512 thr, (cell, 64-col grp)
// blocks 640..687: k2 (g_w2/3/4 -> bf16 A-frag chunks), 512 thr, one 8KB chunk each.
// wf chunk cid = L*16+tt at byte cid*8192; within: kk*1024 + lane*16; lane l holds
// W[k = kk*32+(l>>4)*8+j][outcol = tt*16+(l&15)], j=0..7 (bf16).
__global__ void k12(const float* __restrict__ sup, const float* __restrict__ qry,
                    const float* __restrict__ gw1, const float* __restrict__ gb1,
                    const float* __restrict__ w2, const float* __restrict__ w3,
                    const float* __restrict__ w4,
                    float* __restrict__ ws, unsigned short* __restrict__ wfout) {
    __shared__ float x[258 * 16];
    int bid = blockIdx.x;
    int t = threadIdx.x;
    if (bid >= 640) {
        int cid = bid - 640;          // 0..47
        int L = cid >> 4, tt = cid & 15;
        int kk = t >> 6, l = t & 63;
        const float* W = (L == 0) ? w2 : ((L == 1) ? w3 : w4);
        int nn = tt * 16 + (l & 15);
        int k0 = kk * 32 + (l >> 4) * 8;
        short8 ov;
        #pragma unroll
        for (int j = 0; j < 8; ++j)
            ov[j] = (short)f2bf(W[(size_t)(k0 + j) * 256 + nn]);
        *(short8*)((char*)wfout + (size_t)cid * 8192 + kk * 1024 + l * 16) = ov;
        return;
    }
    int cg = bid & 3;
    int cid = bid >> 2;
    bool isA = (cid < NB * NS);
    int cell = isA ? cid : (cid - NB * NS);
    const float* src = (isA ? sup : qry) + (size_t)cell * 4096;
    ((float4*)x)[t] = ((const float4*)src)[t];
    ((float4*)x)[t + 512] = ((const float4*)src)[t + 512];
    if (t < 16) {
        x[256 * 16 + t] = (float)(t >> 2) * 0.25f;
        x[257 * 16 + t] = (float)(t & 3) * 0.25f;
    }
    __syncthreads();
    int col = cg * 64 + (t & 63);
    int ng = t >> 6;
    float binit = isA ? gb1[col] : 0.0f;
    float ax = binit, ay = binit;
    int koff = isA ? 0 : 258;
    #pragma unroll 4
    for (int k = 0; k < 258; ++k) {
        float wv = gw1[(size_t)(koff + k) * 256 + col];
        float2 xv = *(const float2*)(x + k * 16 + ng * 2);
        ax += xv.x * wv;
        ay += xv.y * wv;
    }
    float* dst = ws + (isA ? A_OFF_F : B_OFF_F) + ((size_t)cell * 16 + ng * 2) * 256 + col;
    dst[0] = ax;
    dst[256] = ay;
}

// ---------------- kernel 3: g-MLP layers 2..4 + pair-sum (128-pair blocks) ----------------
// grid = 1200 blocks = (cell, half): 128 pairs each. 512 threads = 8 waves (wp x wn = 2x4).
// Wave (wp,wn): local pairs [wp*64,+64) (frags m = wp*4+pg), outcols [wn*64,+64).
// H: 64 KB -> 2 blocks/CU -> 4 waves/SIMD (latency hiding; blocks overlap phases).
// W: streamed per-kk from L2, 4x1KB frags, 1-step rolling prefetch.
// acc[4][4] = 64 regs; launch_bounds(512,4) -> 128-reg cap, demand ~125 (no spill).
__launch_bounds__(512, 4)
__global__ void k3_g(const float* __restrict__ wsA, const float* __restrict__ wsB,
                     const unsigned short* __restrict__ wf,
                     const float* __restrict__ gb2, const float* __restrict__ gb3,
                     const float* __restrict__ gb4, float* __restrict__ xf) {
    __shared__ short Hf[32768];   // 64 KB: frag(m,kk) at (m*8+kk)*1024 bytes, m 0..7
    __shared__ float bs[768];
    int bid = blockIdx.x;
    int bqs = bid >> 1, half = bid & 1;
    int b = bqs / 75, rem = bqs % 75, qi = rem / 5, si = rem % 5;
    int t = threadIdx.x;
    int w = t >> 6, l = t & 63;
    int g = l >> 4, c = l & 15;
    int wp = w >> 2, wn = w & 3;
    char* Hb = (char*)Hf;
    const char* wfb = (const char*)wf;

    if (t < 256) { bs[t] = gb2[t]; bs[256 + t] = gb3[t]; bs[512 + t] = gb4[t]; }

    // W step (L=0,kk=0) -> wcur (lands under phase 1)
    short8 wcur[4];
    #pragma unroll
    for (int tti = 0; tti < 4; ++tti)
        wcur[tti] = *(const short8*)(wfb + (size_t)(wn * 4 + tti) * 8192 + l * 16);

    // ---- phase 1: wave w fills frag row m=w: pair_local = w*16 + c,
    // global query-spatial row = half*8 + w, support-spatial = c.
    {
        const float* Arow = wsA + (size_t)(b * NS + si) * 4096 + c * 256;
        const float* Brow = wsB + (size_t)(b * NQ + qi) * 4096 + (half * 8 + w) * 256;
        #pragma unroll
        for (int kk = 0; kk < 8; ++kk) {
            const float* ap = Arow + kk * 32 + g * 8;
            const float* bp = Brow + kk * 32 + g * 8;
            float4 a0 = *(const float4*)ap, a1 = *(const float4*)(ap + 4);
            float4 b0 = *(const float4*)bp, b1 = *(const float4*)(bp + 4);
            uint4 hv;
            hv.x = cvt_pk_bf16(fmaxf(a0.x + b0.x, 0.f), fmaxf(a0.y + b0.y, 0.f));
            hv.y = cvt_pk_bf16(fmaxf(a0.z + b0.z, 0.f), fmaxf(a0.w + b0.w, 0.f));
            hv.z = cvt_pk_bf16(fmaxf(a1.x + b1.x, 0.f), fmaxf(a1.y + b1.y, 0.f));
            hv.w = cvt_pk_bf16(fmaxf(a1.z + b1.z, 0.f), fmaxf(a1.w + b1.w, 0.f));
            *(uint4*)(Hb + (size_t)(w * 8 + kk) * 1024 + l * 16) = hv;
        }
    }
    __syncthreads();   // H1 complete + biases staged

    #pragma unroll 1
    for (int L = 0; L < 3; ++L) {
        f32x4 acc[4][4];
        #pragma unroll
        for (int pg = 0; pg < 4; ++pg)
            #pragma unroll
            for (int tti = 0; tti < 4; ++tti)
                acc[pg][tti] = (f32x4){0.f, 0.f, 0.f, 0.f};

        #pragma unroll
        for (int kk = 0; kk < 8; ++kk) {
            // prefetch next W step (in flight under this step's MFMAs)
            int s = L * 8 + kk + 1; if (s > 23) s = 23;
            int Ln = s >> 3, kn = s & 7;
            short8 wnxt[4];
            #pragma unroll
            for (int tti = 0; tti < 4; ++tti)
                wnxt[tti] = *(const short8*)(wfb +
                    (size_t)(Ln * 16 + wn * 4 + tti) * 8192 + kn * 1024 + l * 16);
            #pragma unroll
            for (int pg = 0; pg < 4; ++pg) {
                short8 h = *(const short8*)(Hb +
                    (size_t)((wp * 4 + pg) * 8 + kk) * 1024 + l * 16);
                #pragma unroll
                for (int tti = 0; tti < 4; ++tti)
                    acc[pg][tti] = mfma16(wcur[tti], h, acc[pg][tti]);
            }
            #pragma unroll
            for (int tti = 0; tti < 4; ++tti) wcur[tti] = wnxt[tti];
        }

        float4 bv[4];
        #pragma unroll
        for (int tti = 0; tti < 4; ++tti)
            bv[tti] = *(const float4*)(bs + L * 256 + wn * 64 + tti * 16 + g * 4);

        if (L < 2) {
            __syncthreads();   // all H reads of layer L done
            // scatter relu(acc+bias) -> next-layer frags:
            // m = wp*4+pg; kk' = wn*2+(tti>>1); dlane = ((tti&1)*2+(g>>1))*16 + c;
            // byte = (g&1)*8
            #pragma unroll
            for (int pg = 0; pg < 4; ++pg) {
                int m = wp * 4 + pg;
                #pragma unroll
                for (int tti = 0; tti < 4; ++tti) {
                    uint2 q;
                    q.x = cvt_pk_bf16(fmaxf(acc[pg][tti][0] + bv[tti].x, 0.f),
                                      fmaxf(acc[pg][tti][1] + bv[tti].y, 0.f));
                    q.y = cvt_pk_bf16(fmaxf(acc[pg][tti][2] + bv[tti].z, 0.f),
                                      fmaxf(acc[pg][tti][3] + bv[tti].w, 0.f));
                    int kk2 = wn * 2 + (tti >> 1);
                    int dlane = ((tti & 1) * 2 + (g >> 1)) * 16 + c;
                    *(uint2*)(Hb + (size_t)(m * 8 + kk2) * 1024 + dlane * 16 + (g & 1) * 8) = q;
                }
            }
            __syncthreads();   // next layer's H published
        } else {
            // final layer: relu + sum over this wave's 64 pairs (4 pg in-reg, 16 c shfl)
            #pragma unroll
            for (int tti = 0; tti < 4; ++tti) {
                float s0 = 0.f, s1 = 0.f, s2 = 0.f, s3 = 0.f;
                #pragma unroll
                for (int pg = 0; pg < 4; ++pg) {
                    s0 += fmaxf(acc[pg][tti][0] + bv[tti].x, 0.f);
                    s1 += fmaxf(acc[pg][tti][1] + bv[tti].y, 0.f);
                    s2 += fmaxf(acc[pg][tti][2] + bv[tti].z, 0.f);
                    s3 += fmaxf(acc[pg][tti][3] + bv[tti].w, 0.f);
                }
                #pragma unroll
                for (int d = 1; d < 16; d <<= 1) {
                    s0 += __shfl_xor(s0, d); s1 += __shfl_xor(s1, d);
                    s2 += __shfl_xor(s2, d); s3 += __shfl_xor(s3, d);
                }
                if (c == 0) {
                    float4 o = {s0, s1, s2, s3};
                    *(float4*)(xf + (((size_t)bqs * 2 + half) * 2 + wp) * 256 +
                               wn * 64 + tti * 16 + g * 4) = o;
                }
            }
        }
    }
}

// ---------------- kernel 4: f-MLP + sigmoid + MSE loss ----------------
// grid = 600 blocks, 1 cell each, 256 threads.
__global__ void k4_f(const float* __restrict__ xf,
                     const float* __restrict__ fw1, const float* __restrict__ fb1,
                     const float* __restrict__ fw2, const float* __restrict__ fb2,
                     const float* __restrict__ fw3, const float* __restrict__ fb3,
                     const float* __restrict__ fw4, const float* __restrict__ fb4,
                     const int* __restrict__ sy, const int* __restrict__ qy,
                     float* __restrict__ out) {
    __shared__ float xb[256], yb[256], y3[32];
    int bqs = blockIdx.x;
    int t = threadIdx.x;
    {
        const float* xr = xf + (size_t)bqs * 1024 + t;
        xb[t] = xr[0] + xr[256] + xr[512] + xr[768];
    }
    __syncthreads();
    float acc = fb1[t];
    #pragma unroll 8
    for (int k = 0; k < 256; ++k)
        acc += xb[k] * fw1[(size_t)k * 256 + t];
    yb[t] = acc > 0.f ? acc : 0.f;
    __syncthreads();
    acc = fb2[t];
    #pragma unroll 8
    for (int k = 0; k < 256; ++k)
        acc += yb[k] * fw2[(size_t)k * 256 + t];
    xb[t] = acc > 0.f ? acc : 0.f;
    __syncthreads();
    if (t < 29) {
        float a = fb3[t];
        #pragma unroll 8
        for (int k = 0; k < 256; ++k) a += xb[k] * fw3[(size_t)k * 29 + t];
        y3[t] = a > 0.f ? a : 0.f;
    }
    __syncthreads();
    if (t == 0) {
        float z = fb4[0];
        for (int k = 0; k < 29; ++k) z += y3[k] * fw4[k];
        float score = 1.0f / (1.0f + __expf(-z));
        int b = bqs / 75, rem = bqs % 75, qi = rem / 5, si = rem % 5;
        float label = (sy[b * NS + si] == qy[b * NQ + qi]) ? 1.0f : 0.0f;
        float d = label - score;
        atomicAdd(out, d * d * 0.125f);
    }
}

// ---------------- launch ----------------
extern "C" void kernel_launch(void* const* d_in, const int* in_sizes, int n_in,
                              void* d_out, int out_size, void* d_ws, size_t ws_size,
                              hipStream_t stream) {
    const float* sup = (const float*)d_in[0];
    const float* qry = (const float*)d_in[1];
    const int*   sy  = (const int*)d_in[2];
    const int*   qy  = (const int*)d_in[3];
    const float* gw1 = (const float*)d_in[4];
    const float* gb1 = (const float*)d_in[5];
    const float* gw2 = (const float*)d_in[6];
    const float* gb2 = (const float*)d_in[7];
    const float* gw3 = (const float*)d_in[8];
    const float* gb3 = (const float*)d_in[9];
    const float* gw4 = (const float*)d_in[10];
    const float* gb4 = (const float*)d_in[11];
    const float* fw1 = (const float*)d_in[12];
    const float* fb1 = (const float*)d_in[13];
    const float* fw2 = (const float*)d_in[14];
    const float* fb2 = (const float*)d_in[15];
    const float* fw3 = (const float*)d_in[16];
    const float* fb3 = (const float*)d_in[17];
    const float* fw4 = (const float*)d_in[18];
    const float* fb4 = (const float*)d_in[19];

    float* ws = (float*)d_ws;
    float* A  = ws + A_OFF_F;
    float* B  = ws + B_OFF_F;
    float* xf = ws + XF_OFF_F;
    unsigned short* wf = (unsigned short*)((char*)d_ws + WF_OFF_BYTES);
    float* out = (float*)d_out;

    hipMemsetAsync(out, 0, sizeof(float), stream);

    k12<<<688, 512, 0, stream>>>(sup, qry, gw1, gb1, gw2, gw3, gw4, ws, wf);
    k3_g<<<1200, 512, 0, stream>>>(A, B, wf, gb2, gb3, gb4, xf);
    k4_f<<<600, 256, 0, stream>>>(xf, fw1, fb1, fw2, fb2, fw3, fb3, fw4, fb4, sy, qy, out);
}

// Round 12
// 125.988 us; speedup vs baseline: 1.6042x; 1.2096x over previous
//
#include <hip/hip_runtime.h>

// ---------------- types / helpers ----------------
typedef __attribute__((ext_vector_type(8))) __bf16 bf16x8;
typedef __attribute__((ext_vector_type(8))) short short8;
typedef __attribute__((ext_vector_type(4))) float f32x4;
typedef unsigned int u32;

static __device__ __forceinline__ unsigned short f2bf(float f) {
    u32 u = __float_as_uint(f);
    u += 0x7FFFu + ((u >> 16) & 1u);
    return (unsigned short)(u >> 16);
}
static __device__ __forceinline__ u32 cvt_pk_bf16(float lo, float hi) {
    u32 r;
    asm("v_cvt_pk_bf16_f32 %0, %1, %2" : "=v"(r) : "v"(lo), "v"(hi));
    return r;
}
static __device__ __forceinline__ bf16x8 as_bf16x8(short8 v) {
    return __builtin_bit_cast(bf16x8, v);
}
static __device__ __forceinline__ f32x4 mfma16(short8 a, short8 b, f32x4 c) {
    return __builtin_amdgcn_mfma_f32_16x16x32_bf16(as_bf16x8(a), as_bf16x8(b), c, 0, 0, 0);
}

// problem sizes
#define NB 8
#define NS 5
#define NQ 15
// ws layout (floats)
#define A_OFF_F 0
#define B_OFF_F (640*256)                        // 163840
#define XF_OFF_F (B_OFF_F + 1920*256)            // 655360
#define WF_OFF_BYTES ((XF_OFF_F + 600*1024)*4)   // 5079040, 16B aligned
#define WF1_OFF_BYTES (WF_OFF_BYTES + 48*8192)   // g-frags 384KB, then W1-frags

// ---------------- kernel A: all weight fragments ----------------
// blocks 0..47: g_w2/3/4 -> bf16 A-frag chunks, chunk cid = L*16+tt at byte cid*8192;
//   within: kk*1024 + lane*16; lane l holds W[k=kk*32+(l>>4)*8+j][outcol=tt*16+(l&15)].
// blocks 48..79: W1 frags (K padded 258->288): chunk c1 = S*16+tt at wf1 + c1*9216;
//   within: kk*1024 + lane*16 (kk 0..8); W1 row = S*258 + kb for kb<258 (covers
//   features AND coord rows 256/257 resp. 514/515), zero for kb>=258.
__global__ void kA(const float* __restrict__ w2, const float* __restrict__ w3,
                   const float* __restrict__ w4, const float* __restrict__ w1,
                   unsigned short* __restrict__ wf, unsigned short* __restrict__ wf1) {
    int bid = blockIdx.x;
    int l = threadIdx.x;
    if (bid < 48) {
        int L = bid >> 4, tt = bid & 15;
        const float* W = (L == 0) ? w2 : ((L == 1) ? w3 : w4);
        int nn = tt * 16 + (l & 15);
        #pragma unroll
        for (int kk = 0; kk < 8; ++kk) {
            int k0 = kk * 32 + (l >> 4) * 8;
            short8 ov;
            #pragma unroll
            for (int j = 0; j < 8; ++j)
                ov[j] = (short)f2bf(W[(size_t)(k0 + j) * 256 + nn]);
            *(short8*)((char*)wf + (size_t)bid * 8192 + kk * 1024 + l * 16) = ov;
        }
        return;
    }
    int c1 = bid - 48;                 // S*16 + tt
    int S = c1 >> 4, tt = c1 & 15;
    int nn = tt * 16 + (l & 15);
    for (int kk = 0; kk < 9; ++kk) {
        int k0 = kk * 32 + (l >> 4) * 8;
        short8 ov;
        #pragma unroll
        for (int j = 0; j < 8; ++j) {
            int kb = k0 + j;
            float v = (kb < 258) ? w1[(size_t)(S * 258 + kb) * 256 + nn] : 0.0f;
            ov[j] = (short)f2bf(v);
        }
        *(short8*)((char*)wf1 + (size_t)c1 * 9216 + kk * 1024 + l * 16) = ov;
    }
}

// ---------------- kernel B: layer-1 rows via MFMA ----------------
// grid = 40 blocks (10 sup + 30 qry), 4 cells each (M = 64 rows), 512 thr = 8 waves.
// X staged to LDS in B-frag layout (coord rows synthesized, K zero-padded to 288);
// W1 frags rolling-prefetched from wf1; epilogue float4-stores into the f32
// [cell][row n/m][256] layout k3 consumes. gb1 folded into the sup (A) side only.
__launch_bounds__(512, 1)
__global__ void kB(const float* __restrict__ sup, const float* __restrict__ qry,
                   const unsigned short* __restrict__ wf1,
                   const float* __restrict__ gb1, float* __restrict__ ws) {
    __shared__ short Xf[18432];       // 36 KB: frag(m,kk) at (m*9+kk)*1024 bytes
    int bid = blockIdx.x;
    bool isA = (bid < 10);
    int S = isA ? 0 : 1;
    int cellbase = isA ? bid * 4 : (bid - 10) * 4;
    const float* src = isA ? sup : qry;
    float* dst0 = ws + (isA ? A_OFF_F : B_OFF_F);
    int t = threadIdx.x;
    int w = t >> 6, l = t & 63;
    int g = l >> 4, c = l & 15;
    char* Xb = (char*)Xf;
    const char* w1b = (const char*)wf1;

    // ---- stage X frags: frag m = local cell, lane (g,c): k = kk*32+g*8+j, n = c
    for (int idx = w; idx < 36; idx += 8) {
        int m = idx / 9, kk = idx % 9;
        const float* xp = src + (size_t)(cellbase + m) * 4096;
        int kbase = kk * 32 + g * 8;
        float v[8];
        #pragma unroll
        for (int j = 0; j < 8; ++j) {
            int kb = kbase + j;
            float x;
            if (kb < 256)       x = xp[(size_t)kb * 16 + c];
            else if (kb == 256) x = (float)(c >> 2) * 0.25f;
            else if (kb == 257) x = (float)(c & 3) * 0.25f;
            else                x = 0.0f;
            v[j] = x;
        }
        uint4 hv;
        hv.x = cvt_pk_bf16(v[0], v[1]);
        hv.y = cvt_pk_bf16(v[2], v[3]);
        hv.z = cvt_pk_bf16(v[4], v[5]);
        hv.w = cvt_pk_bf16(v[6], v[7]);
        *(uint4*)(Xb + (size_t)(m * 9 + kk) * 1024 + l * 16) = hv;
    }
    __syncthreads();

    int wp = w >> 2, wn = w & 3;
    const char* wbase = w1b + (size_t)(S * 16 + wn * 4) * 9216;   // 4 tt chunks
    short8 wcur[4];
    #pragma unroll
    for (int tti = 0; tti < 4; ++tti)
        wcur[tti] = *(const short8*)(wbase + (size_t)tti * 9216 + l * 16);

    f32x4 acc[2][4];
    #pragma unroll
    for (int pg = 0; pg < 2; ++pg)
        #pragma unroll
        for (int tti = 0; tti < 4; ++tti)
            acc[pg][tti] = (f32x4){0.f, 0.f, 0.f, 0.f};

    #pragma unroll
    for (int kk = 0; kk < 9; ++kk) {
        int kn = kk + 1; if (kn > 8) kn = 8;
        short8 wnxt[4];
        #pragma unroll
        for (int tti = 0; tti < 4; ++tti)
            wnxt[tti] = *(const short8*)(wbase + (size_t)tti * 9216 + kn * 1024 + l * 16);
        #pragma unroll
        for (int pg = 0; pg < 2; ++pg) {
            short8 h = *(const short8*)(Xb + (size_t)((wp * 2 + pg) * 9 + kk) * 1024 + l * 16);
            #pragma unroll
            for (int tti = 0; tti < 4; ++tti)
                acc[pg][tti] = mfma16(wcur[tti], h, acc[pg][tti]);
        }
        #pragma unroll
        for (int tti = 0; tti < 4; ++tti) wcur[tti] = wnxt[tti];
    }

    // ---- epilogue: row = (cellbase + wp*2+pg)*16 + c, col = wn*64+tti*16+g*4+r
    #pragma unroll
    for (int tti = 0; tti < 4; ++tti) {
        int col0 = wn * 64 + tti * 16 + g * 4;
        float4 bv = {0.f, 0.f, 0.f, 0.f};
        if (S == 0) bv = *(const float4*)(gb1 + col0);
        #pragma unroll
        for (int pg = 0; pg < 2; ++pg) {
            int row = (cellbase + wp * 2 + pg) * 16 + c;
            float4 o;
            o.x = acc[pg][tti][0] + bv.x;
            o.y = acc[pg][tti][1] + bv.y;
            o.z = acc[pg][tti][2] + bv.z;
            o.w = acc[pg][tti][3] + bv.w;
            *(float4*)(dst0 + (size_t)row * 256 + col0) = o;
        }
    }
}

// ---------------- kernel 3: g-MLP layers 2..4 + pair-sum (128-pair blocks) ----------------
// (unchanged from round 11 — verified)
__launch_bounds__(512, 4)
__global__ void k3_g(const float* __restrict__ wsA, const float* __restrict__ wsB,
                     const unsigned short* __restrict__ wf,
                     const float* __restrict__ gb2, const float* __restrict__ gb3,
                     const float* __restrict__ gb4, float* __restrict__ xf) {
    __shared__ short Hf[32768];   // 64 KB: frag(m,kk) at (m*8+kk)*1024 bytes, m 0..7
    __shared__ float bs[768];
    int bid = blockIdx.x;
    int bqs = bid >> 1, half = bid & 1;
    int b = bqs / 75, rem = bqs % 75, qi = rem / 5, si = rem % 5;
    int t = threadIdx.x;
    int w = t >> 6, l = t & 63;
    int g = l >> 4, c = l & 15;
    int wp = w >> 2, wn = w & 3;
    char* Hb = (char*)Hf;
    const char* wfb = (const char*)wf;

    if (t < 256) { bs[t] = gb2[t]; bs[256 + t] = gb3[t]; bs[512 + t] = gb4[t]; }

    short8 wcur[4];
    #pragma unroll
    for (int tti = 0; tti < 4; ++tti)
        wcur[tti] = *(const short8*)(wfb + (size_t)(wn * 4 + tti) * 8192 + l * 16);

    {
        const float* Arow = wsA + (size_t)(b * NS + si) * 4096 + c * 256;
        const float* Brow = wsB + (size_t)(b * NQ + qi) * 4096 + (half * 8 + w) * 256;
        #pragma unroll
        for (int kk = 0; kk < 8; ++kk) {
            const float* ap = Arow + kk * 32 + g * 8;
            const float* bp = Brow + kk * 32 + g * 8;
            float4 a0 = *(const float4*)ap, a1 = *(const float4*)(ap + 4);
            float4 b0 = *(const float4*)bp, b1 = *(const float4*)(bp + 4);
            uint4 hv;
            hv.x = cvt_pk_bf16(fmaxf(a0.x + b0.x, 0.f), fmaxf(a0.y + b0.y, 0.f));
            hv.y = cvt_pk_bf16(fmaxf(a0.z + b0.z, 0.f), fmaxf(a0.w + b0.w, 0.f));
            hv.z = cvt_pk_bf16(fmaxf(a1.x + b1.x, 0.f), fmaxf(a1.y + b1.y, 0.f));
            hv.w = cvt_pk_bf16(fmaxf(a1.z + b1.z, 0.f), fmaxf(a1.w + b1.w, 0.f));
            *(uint4*)(Hb + (size_t)(w * 8 + kk) * 1024 + l * 16) = hv;
        }
    }
    __syncthreads();

    #pragma unroll 1
    for (int L = 0; L < 3; ++L) {
        f32x4 acc[4][4];
        #pragma unroll
        for (int pg = 0; pg < 4; ++pg)
            #pragma unroll
            for (int tti = 0; tti < 4; ++tti)
                acc[pg][tti] = (f32x4){0.f, 0.f, 0.f, 0.f};

        #pragma unroll
        for (int kk = 0; kk < 8; ++kk) {
            int s = L * 8 + kk + 1; if (s > 23) s = 23;
            int Ln = s >> 3, kn = s & 7;
            short8 wnxt[4];
            #pragma unroll
            for (int tti = 0; tti < 4; ++tti)
                wnxt[tti] = *(const short8*)(wfb +
                    (size_t)(Ln * 16 + wn * 4 + tti) * 8192 + kn * 1024 + l * 16);
            #pragma unroll
            for (int pg = 0; pg < 4; ++pg) {
                short8 h = *(const short8*)(Hb +
                    (size_t)((wp * 4 + pg) * 8 + kk) * 1024 + l * 16);
                #pragma unroll
                for (int tti = 0; tti < 4; ++tti)
                    acc[pg][tti] = mfma16(wcur[tti], h, acc[pg][tti]);
            }
            #pragma unroll
            for (int tti = 0; tti < 4; ++tti) wcur[tti] = wnxt[tti];
        }

        float4 bv[4];
        #pragma unroll
        for (int tti = 0; tti < 4; ++tti)
            bv[tti] = *(const float4*)(bs + L * 256 + wn * 64 + tti * 16 + g * 4);

        if (L < 2) {
            __syncthreads();
            #pragma unroll
            for (int pg = 0; pg < 4; ++pg) {
                int m = wp * 4 + pg;
                #pragma unroll
                for (int tti = 0; tti < 4; ++tti) {
                    uint2 q;
                    q.x = cvt_pk_bf16(fmaxf(acc[pg][tti][0] + bv[tti].x, 0.f),
                                      fmaxf(acc[pg][tti][1] + bv[tti].y, 0.f));
                    q.y = cvt_pk_bf16(fmaxf(acc[pg][tti][2] + bv[tti].z, 0.f),
                                      fmaxf(acc[pg][tti][3] + bv[tti].w, 0.f));
                    int kk2 = wn * 2 + (tti >> 1);
                    int dlane = ((tti & 1) * 2 + (g >> 1)) * 16 + c;
                    *(uint2*)(Hb + (size_t)(m * 8 + kk2) * 1024 + dlane * 16 + (g & 1) * 8) = q;
                }
            }
            __syncthreads();
        } else {
            #pragma unroll
            for (int tti = 0; tti < 4; ++tti) {
                float s0 = 0.f, s1 = 0.f, s2 = 0.f, s3 = 0.f;
                #pragma unroll
                for (int pg = 0; pg < 4; ++pg) {
                    s0 += fmaxf(acc[pg][tti][0] + bv[tti].x, 0.f);
                    s1 += fmaxf(acc[pg][tti][1] + bv[tti].y, 0.f);
                    s2 += fmaxf(acc[pg][tti][2] + bv[tti].z, 0.f);
                    s3 += fmaxf(acc[pg][tti][3] + bv[tti].w, 0.f);
                }
                #pragma unroll
                for (int d = 1; d < 16; d <<= 1) {
                    s0 += __shfl_xor(s0, d); s1 += __shfl_xor(s1, d);
                    s2 += __shfl_xor(s2, d); s3 += __shfl_xor(s3, d);
                }
                if (c == 0) {
                    float4 o = {s0, s1, s2, s3};
                    *(float4*)(xf + (((size_t)bqs * 2 + half) * 2 + wp) * 256 +
                               wn * 64 + tti * 16 + g * 4) = o;
                }
            }
        }
    }
}

// ---------------- kernel 4: f-MLP + sigmoid + MSE loss ----------------
// grid = 150 blocks x 4 cells, 256 threads; fw loads reused 4x.
__global__ void k4_f(const float* __restrict__ xf,
                     const float* __restrict__ fw1, const float* __restrict__ fb1,
                     const float* __restrict__ fw2, const float* __restrict__ fb2,
                     const float* __restrict__ fw3, const float* __restrict__ fb3,
                     const float* __restrict__ fw4, const float* __restrict__ fb4,
                     const int* __restrict__ sy, const int* __restrict__ qy,
                     float* __restrict__ out) {
    __shared__ float xb[4][256], yb[4][256], y3[4][32];
    int base = blockIdx.x * 4;
    int t = threadIdx.x;
    #pragma unroll
    for (int cc = 0; cc < 4; ++cc) {
        const float* xr = xf + (size_t)(base + cc) * 1024 + t;
        xb[cc][t] = xr[0] + xr[256] + xr[512] + xr[768];
    }
    __syncthreads();
    float acc[4];
    #pragma unroll
    for (int cc = 0; cc < 4; ++cc) acc[cc] = fb1[t];
    #pragma unroll 8
    for (int k = 0; k < 256; ++k) {
        float wv = fw1[(size_t)k * 256 + t];
        #pragma unroll
        for (int cc = 0; cc < 4; ++cc) acc[cc] += xb[cc][k] * wv;
    }
    #pragma unroll
    for (int cc = 0; cc < 4; ++cc) yb[cc][t] = acc[cc] > 0.f ? acc[cc] : 0.f;
    __syncthreads();
    #pragma unroll
    for (int cc = 0; cc < 4; ++cc) acc[cc] = fb2[t];
    #pragma unroll 8
    for (int k = 0; k < 256; ++k) {
        float wv = fw2[(size_t)k * 256 + t];
        #pragma unroll
        for (int cc = 0; cc < 4; ++cc) acc[cc] += yb[cc][k] * wv;
    }
    #pragma unroll
    for (int cc = 0; cc < 4; ++cc) xb[cc][t] = acc[cc] > 0.f ? acc[cc] : 0.f;
    __syncthreads();
    if (t < 116) {
        int cc = t / 29, col = t % 29;
        float a = fb3[col];
        #pragma unroll 8
        for (int k = 0; k < 256; ++k) a += xb[cc][k] * fw3[(size_t)k * 29 + col];
        y3[cc][col] = a > 0.f ? a : 0.f;
    }
    __syncthreads();
    if (t < 4) {
        int cc = t;
        float z = fb4[0];
        for (int k = 0; k < 29; ++k) z += y3[cc][k] * fw4[k];
        float score = 1.0f / (1.0f + __expf(-z));
        int bqs = base + cc;
        int b = bqs / 75, rem = bqs % 75, qi = rem / 5, si = rem % 5;
        float label = (sy[b * NS + si] == qy[b * NQ + qi]) ? 1.0f : 0.0f;
        float d = label - score;
        atomicAdd(out, d * d * 0.125f);
    }
}

// ---------------- launch ----------------
extern "C" void kernel_launch(void* const* d_in, const int* in_sizes, int n_in,
                              void* d_out, int out_size, void* d_ws, size_t ws_size,
                              hipStream_t stream) {
    const float* sup = (const float*)d_in[0];
    const float* qry = (const float*)d_in[1];
    const int*   sy  = (const int*)d_in[2];
    const int*   qy  = (const int*)d_in[3];
    const float* gw1 = (const float*)d_in[4];
    const float* gb1 = (const float*)d_in[5];
    const float* gw2 = (const float*)d_in[6];
    const float* gb2 = (const float*)d_in[7];
    const float* gw3 = (const float*)d_in[8];
    const float* gb3 = (const float*)d_in[9];
    const float* gw4 = (const float*)d_in[10];
    const float* gb4 = (const float*)d_in[11];
    const float* fw1 = (const float*)d_in[12];
    const float* fb1 = (const float*)d_in[13];
    const float* fw2 = (const float*)d_in[14];
    const float* fb2 = (const float*)d_in[15];
    const float* fw3 = (const float*)d_in[16];
    const float* fb3 = (const float*)d_in[17];
    const float* fw4 = (const float*)d_in[18];
    const float* fb4 = (const float*)d_in[19];

    float* ws = (float*)d_ws;
    float* A  = ws + A_OFF_F;
    float* B  = ws + B_OFF_F;
    float* xf = ws + XF_OFF_F;
    unsigned short* wf  = (unsigned short*)((char*)d_ws + WF_OFF_BYTES);
    unsigned short* wf1 = (unsigned short*)((char*)d_ws + WF1_OFF_BYTES);
    float* out = (float*)d_out;

    hipMemsetAsync(out, 0, sizeof(float), stream);

    kA<<<80, 64, 0, stream>>>(gw2, gw3, gw4, gw1, wf, wf1);
    kB<<<40, 512, 0, stream>>>(sup, qry, wf1, gb1, ws);
    k3_g<<<1200, 512, 0, stream>>>(A, B, wf, gb2, gb3, gb4, xf);
    k4_f<<<150, 256, 0, stream>>>(xf, fw1, fb1, fw2, fb2, fw3, fb3, fw4, fb4, sy, qy, out);
}